// Round 3
// baseline (608.746 us; speedup 1.0000x reference)
//
#include <hip/hip_runtime.h>
#include <hip/hip_bf16.h>

using bf16 = __hip_bfloat16;
typedef __bf16 bf16x8 __attribute__((ext_vector_type(8)));
typedef float f32x4 __attribute__((ext_vector_type(4)));

#define MFMA16(A, B, C) __builtin_amdgcn_mfma_f32_16x16x32_bf16((A), (B), (C), 0, 0, 0)

__device__ __forceinline__ void store_elem(bf16* p, float v) { *p = __float2bfloat16(v); }
__device__ __forceinline__ void store_elem(float* p, float v) { *p = v; }

__device__ __forceinline__ unsigned short f2bu(float x) {
    bf16 t = __float2bfloat16(x);
    return *(unsigned short*)&t;
}

// async global->LDS 16B per lane; LDS dest = wave-uniform base + lane*16.
__device__ __forceinline__ void async_cp16(const bf16* g, bf16* l) {
    __builtin_amdgcn_global_load_lds(
        (const __attribute__((address_space(1))) void*)g,
        (__attribute__((address_space(3))) void*)l, 16, 0, 0);
}

// ---------------------------------------------------------------------------
__global__ void cvt_fp32_bf16(const float* __restrict__ src, bf16* __restrict__ dst) {
    int i = (blockIdx.x * 256 + threadIdx.x) * 4;
    float4 v = *(const float4*)(src + i);
    bf16 o[4] = {__float2bfloat16(v.x), __float2bfloat16(v.y),
                 __float2bfloat16(v.z), __float2bfloat16(v.w)};
    *(uint2*)(dst + i) = *(const uint2*)o;
}

// ---------------------------------------------------------------------------
__global__ void wtrans(const float* __restrict__ src, bf16* __restrict__ dst,
                       int K, int N) {
    __shared__ bf16 t[32][33];
    int n0 = blockIdx.x * 32, k0 = blockIdx.y * 32;
    #pragma unroll
    for (int i = 0; i < 4; ++i) {
        int r = threadIdx.y + i * 8;
        t[r][threadIdx.x] = __float2bfloat16(src[(size_t)(k0 + r) * N + n0 + threadIdx.x]);
    }
    __syncthreads();
    #pragma unroll
    for (int i = 0; i < 4; ++i) {
        int r = threadIdx.y + i * 8;
        dst[(size_t)(n0 + r) * K + k0 + threadIdx.x] = t[threadIdx.x][r];
    }
}

__global__ void zerofill(bf16* __restrict__ p) {
    p[blockIdx.x * 256 + threadIdx.x] = __float2bfloat16(0.0f);
}

// ---------------------------------------------------------------------------
// GEMM: C[M][N] = A[M][K] @ Bt[N][K]^T. global_load_lds staging (m97 pattern).
// ---------------------------------------------------------------------------
template <typename CT>
__global__ __launch_bounds__(256) void gemm_bt(
    const bf16* __restrict__ A, int lda,
    const bf16* __restrict__ Bt, int ldb,
    CT* __restrict__ C, int ldc, int K) {
    __shared__ bf16 As[128 * 32];
    __shared__ bf16 Bs[128 * 32];
    const int m0 = blockIdx.y * 128;
    const int n0 = blockIdx.x * 128;
    const int tid = threadIdx.x;
    const int lane = tid & 63;
    const int wave = tid >> 6;
    const int wm = (wave >> 1) * 64;
    const int wn = (wave & 1) * 64;
    const int lr = lane & 15;
    const int lq = lane >> 4;
    const int sr = tid >> 2;
    const int sc = (tid & 3) * 8;
    const int wbase = wave * 512;

    f32x4 acc[4][4] = {};

    for (int k0 = 0; k0 < K; k0 += 32) {
        __syncthreads();
        async_cp16(A + (size_t)(m0 + sr) * lda + k0 + sc, As + wbase);
        async_cp16(A + (size_t)(m0 + sr + 64) * lda + k0 + sc, As + 2048 + wbase);
        async_cp16(Bt + (size_t)(n0 + sr) * ldb + k0 + sc, Bs + wbase);
        async_cp16(Bt + (size_t)(n0 + sr + 64) * ldb + k0 + sc, Bs + 2048 + wbase);
        __syncthreads();
        bf16x8 af[4], bfr[4];
        #pragma unroll
        for (int t = 0; t < 4; ++t) {
            af[t]  = *(const bf16x8*)(As + (wm + t * 16 + lr) * 32 + lq * 8);
            bfr[t] = *(const bf16x8*)(Bs + (wn + t * 16 + lr) * 32 + lq * 8);
        }
        #pragma unroll
        for (int mt = 0; mt < 4; ++mt)
            #pragma unroll
            for (int nt = 0; nt < 4; ++nt)
                acc[mt][nt] = MFMA16(af[mt], bfr[nt], acc[mt][nt]);
    }
    #pragma unroll
    for (int mt = 0; mt < 4; ++mt)
        #pragma unroll
        for (int nt = 0; nt < 4; ++nt)
            #pragma unroll
            for (int r = 0; r < 4; ++r) {
                int row = m0 + wm + mt * 16 + lq * 4 + r;
                int col = n0 + wn + nt * 16 + lr;
                store_elem(C + (size_t)row * ldc + col, acc[mt][nt][r]);
            }
}

// ---------------------------------------------------------------------------
// kv GEMM, split epilogue: k_nope -> kbuf, v -> vT (transposed). grid (32,32).
// ---------------------------------------------------------------------------
__global__ __launch_bounds__(256) void gemm_kv(
    const bf16* __restrict__ A, int lda,
    const bf16* __restrict__ Bt, int ldb,
    bf16* __restrict__ kbuf, bf16* __restrict__ vT, int K) {
    __shared__ bf16 As[128 * 32];
    __shared__ bf16 Bs[128 * 32];
    const int m0 = blockIdx.y * 128;
    const int n0 = blockIdx.x * 128;
    const int tid = threadIdx.x;
    const int lane = tid & 63;
    const int wave = tid >> 6;
    const int wm = (wave >> 1) * 64;
    const int wn = (wave & 1) * 64;
    const int lr = lane & 15;
    const int lq = lane >> 4;
    const int sr = tid >> 2;
    const int sc = (tid & 3) * 8;
    const int wbase = wave * 512;

    f32x4 acc[4][4] = {};

    for (int k0 = 0; k0 < K; k0 += 32) {
        __syncthreads();
        async_cp16(A + (size_t)(m0 + sr) * lda + k0 + sc, As + wbase);
        async_cp16(A + (size_t)(m0 + sr + 64) * lda + k0 + sc, As + 2048 + wbase);
        async_cp16(Bt + (size_t)(n0 + sr) * ldb + k0 + sc, Bs + wbase);
        async_cp16(Bt + (size_t)(n0 + sr + 64) * ldb + k0 + sc, Bs + 2048 + wbase);
        __syncthreads();
        bf16x8 af[4], bfr[4];
        #pragma unroll
        for (int t = 0; t < 4; ++t) {
            af[t]  = *(const bf16x8*)(As + (wm + t * 16 + lr) * 32 + lq * 8);
            bfr[t] = *(const bf16x8*)(Bs + (wn + t * 16 + lr) * 32 + lq * 8);
        }
        #pragma unroll
        for (int mt = 0; mt < 4; ++mt)
            #pragma unroll
            for (int nt = 0; nt < 4; ++nt)
                acc[mt][nt] = MFMA16(af[mt], bfr[nt], acc[mt][nt]);
    }
    #pragma unroll
    for (int mt = 0; mt < 4; ++mt)
        #pragma unroll
        for (int nt = 0; nt < 4; ++nt) {
            int colbase = n0 + wn + nt * 16;
            int h = colbase >> 8;
            int rr = (colbase & 255) + lr;
            #pragma unroll
            for (int r = 0; r < 4; ++r) {
                int row = m0 + wm + mt * 16 + lq * 4 + r;
                bf16 val = __float2bfloat16(acc[mt][nt][r]);
                if (rr < 128) {
                    kbuf[(size_t)row * 2048 + h * 128 + rr] = val;
                } else {
                    int dv = rr - 128;
                    int b = row >> 11, s = row & 2047;
                    vT[((size_t)((b * 16 + h) * 128 + dv)) * 2048 + s] = val;
                }
            }
        }
}

// ---------------------------------------------------------------------------
__global__ void rope_kernel(bf16* __restrict__ XW) {
    int v = blockIdx.x;
    int row = blockIdx.y * 4 + threadIdx.y;
    int i = threadIdx.x;
    int s = row & 2047;
    int cbase = (v < 16) ? v * 192 + 128 : 3072;
    size_t base = (size_t)row * 3712 + cbase;
    float xi = __bfloat162float(XW[base + i]);
    float xp = __shfl_xor(xi, 32);
    int j = i & 31;
    float inv = exp2f(-(float)j * (13.287712379549449f / 32.0f));
    float ang = (float)s * inv;
    float c = cosf(ang), sn = sinf(ang);
    float res = (i < 32) ? (xi * c - xp * sn) : (xi * c + xp * sn);
    XW[base + i] = __float2bfloat16(res);
}

// ---------------------------------------------------------------------------
// Flash attention R3: block-cooperative K staging via global_load_lds.
//
// R2 post-mortem: per-lane K loads (24 b128/tile) can only pipeline a few
// deep at the available VGPR budget -> ~2-3k exposed L2-latency cycles per
// tile (70% of SIMD cycles idle). global_load_lds stages with ZERO VGPRs for
// in-flight data, so depth is free -- but needs tile sharing across waves.
//
// Decomposition: block = (bh, big-unit pair (U,15-U) of 128 q rows, key
// half). ntiles(U)=2U+2 (KVBLK=64); per-unit halves of U+1 tiles each =>
// every block runs exactly (U+1)+((15-U)+1) = 17 tiles. 512 blocks, 4 waves,
// wave w owns rows U*128+32w (per-wave compute identical to R2).
//
// 2-phase pipeline per tile: [rope loads (per-lane, FIRST so their vmcnt
// wait doesn't drain staging)] -> [stage K-nope(t+1) -> Ks[par^1]] ->
// [V loads + S^T + softmax + PV] -> __syncthreads (drain lands after PV:
// staging latency hides under a full tile of compute).
//
// Ks is source-pre-swizzled (rule 21): linear LDS dest, per-lane source
// chunk j^(row&7), read with the same XOR -> 2-way bank access (free)
// instead of 16-way on 256B rows. LDS 50.7KB -> 2 blocks/CU, 8 waves/CU.
// ---------------------------------------------------------------------------
__global__ __launch_bounds__(256, 2) void attn_kernel(
    const bf16* __restrict__ XW, const bf16* __restrict__ kbuf,
    const bf16* __restrict__ vT, bf16* __restrict__ attn_out,
    bf16* __restrict__ opart, float* __restrict__ mlbuf) {
    const int bid = blockIdx.x;
    const int half = bid >> 8;          // key-chunk index
    const int rem = bid & 255;
    const int bh = rem & 31;            // bid%8 == bh%8 -> XCD clustering
    const int p = rem >> 5;             // big-unit pair in [0,8)
    const int b = bh >> 4, h = bh & 15;
    const int tid = threadIdx.x;
    const int wave = tid >> 6;
    const int lane = tid & 63;
    const int lr = lane & 15, lq = lane >> 4;

    __shared__ bf16 Ks[2][64 * 128];    // K-nope tile, swizzled, dbuf (32KB)
    __shared__ bf16 Pm[4 * 32 * 72];    // per-wave 32x72 P; 16x136 Tr epilogue
    bf16* Pw = Pm + wave * (32 * 72);

    const bf16* xwb = XW + (size_t)b * 2048 * 3712;
    const bf16* kb  = kbuf + (size_t)b * 2048 * 2048 + h * 128;
    const bf16* rp  = xwb + 3072;       // k_rope columns
    const bf16* vTb = vT + (size_t)bh * 128 * 2048;

    const float sc2 = 0.07216878364870323f * 1.4426950408889634f;  // scale*log2e

    // Staging: 16 instrs/tile, 4 per wave. Instr i covers rows i*4..i*4+3
    // (256B each). Lane l: row r = i*4 + (l>>4), LDS chunk j' = l&15 holds
    // source chunk j' ^ (r&7)  (inverse of the read-side XOR).
    const int s_rsub = lane >> 4;       // row within instr
    const int s_j    = lane & 15;       // dest 16B chunk
#define STAGE_K(N0, BUF) do {                                                  \
        _Pragma("unroll")                                                      \
        for (int k_ = 0; k_ < 4; ++k_) {                                       \
            int i_ = wave * 4 + k_;                                            \
            int r_ = i_ * 4 + s_rsub;                                          \
            int j_ = s_j ^ (r_ & 7);                                           \
            async_cp16(kb + (size_t)((N0) + r_) * 2048 + j_ * 8,               \
                       (BUF) + i_ * 512);                                      \
        }                                                                      \
    } while (0)

    // Read-side swizzled 16B-chunk offsets (elements) for S^T LDS reads:
    // row = mt*16+lr (row&7 == lr&7), chunk = c*4+lq.
    const int rs = lr & 7;
    int koff[4];
    #pragma unroll
    for (int c = 0; c < 4; ++c) koff[c] = ((c * 4 + lq) ^ rs) * 8;

    #pragma unroll 1
    for (int ph = 0; ph < 2; ++ph) {
        const int u = ph ? (15 - p) : p;       // big unit in [0,16)
        const int qw = u * 128 + wave * 32;    // this wave's first q row
        const int hnt = u + 1;                 // tiles per half
        const int t0 = half ? hnt : 0;
        const int t1 = half ? (2 * u + 2) : hnt;

        // Q B-frags: [n=q(lane&15)][k=lq*8..], 2 nf groups x 6 feature chunks
        bf16x8 qf[2][6];
        #pragma unroll
        for (int nf = 0; nf < 2; ++nf) {
            size_t ro = (size_t)(qw + nf * 16 + lr) * 3712 + h * 192;
            #pragma unroll
            for (int c = 0; c < 6; ++c)
                qf[nf][c] = *(const bf16x8*)(xwb + ro + c * 32 + lq * 8);
        }

        f32x4 o[2][8] = {};      // O^T: [nf][dt], col=q, row=dv
        float m_i[2], l_i[2];
        m_i[0] = m_i[1] = -1e30f;
        l_i[0] = l_i[1] = 0.0f;

        // prologue: stage first tile (all waves past prior Ks reads: the
        // previous ph's loop ended with __syncthreads)
        STAGE_K(t0 * 64, Ks[0]);
        __syncthreads();
        int par = 0;

        for (int t = t0; t < t1; ++t) {
            const int n0 = t * 64;
            const bf16* Kc = Ks[par];

            // ---- rope loads FIRST (their wait must not drain staging) ----
            bf16x8 rf[2][4];
            #pragma unroll
            for (int c = 0; c < 2; ++c)
                #pragma unroll
                for (int mt = 0; mt < 4; ++mt)
                    rf[c][mt] = *(const bf16x8*)(rp + (size_t)(n0 + mt * 16 + lr) * 3712 + c * 32 + lq * 8);

            // ---- stage next tile into the other buffer (async) ----
            if (t + 1 < t1) STAGE_K((t + 1) * 64, Ks[par ^ 1]);

            if (n0 < qw + 32) {  // wave-uniform: skip fully-masked tiles
                // ---- V prefetch (latency hides under softmax) ----
                bf16x8 vf[2][8];
                #pragma unroll
                for (int kt = 0; kt < 2; ++kt)
                    #pragma unroll
                    for (int dt = 0; dt < 8; ++dt)
                        vf[kt][dt] = *(const bf16x8*)(vTb + (size_t)(dt * 16 + lr) * 2048 + n0 + kt * 32 + lq * 8);

                // ---- S^T = K Q^T: 16 LDS + 8 reg frags, 48 MFMAs ----
                f32x4 st[4][2] = {};   // [mt(key)][nf(q)]
                __builtin_amdgcn_s_setprio(1);
                #pragma unroll
                for (int c = 0; c < 4; ++c) {
                    #pragma unroll
                    for (int mt = 0; mt < 4; ++mt) {
                        bf16x8 kf = *(const bf16x8*)(Kc + (mt * 16 + lr) * 128 + koff[c]);
                        st[mt][0] = MFMA16(kf, qf[0][c], st[mt][0]);
                        st[mt][1] = MFMA16(kf, qf[1][c], st[mt][1]);
                    }
                }
                #pragma unroll
                for (int c = 0; c < 2; ++c) {
                    #pragma unroll
                    for (int mt = 0; mt < 4; ++mt) {
                        st[mt][0] = MFMA16(rf[c][mt], qf[0][c + 4], st[mt][0]);
                        st[mt][1] = MFMA16(rf[c][mt], qf[1][c + 4], st[mt][1]);
                    }
                }
                __builtin_amdgcn_s_setprio(0);

                // ---- online softmax, raw-domain max, fma-folded scale ----
                #pragma unroll
                for (int nf = 0; nf < 2; ++nf) {
                    int q = qw + nf * 16 + lr;
                    f32x4 a[4];
                    #pragma unroll
                    for (int mt = 0; mt < 4; ++mt) a[mt] = st[mt][nf];
                    if (n0 + 63 > qw + nf * 16) {   // diagonal tile only
                        #pragma unroll
                        for (int mt = 0; mt < 4; ++mt)
                            #pragma unroll
                            for (int r = 0; r < 4; ++r) {
                                int kid = n0 + mt * 16 + lq * 4 + r;
                                if (kid > q) a[mt][r] = -1e30f;
                            }
                    }
                    f32x4 m4 = a[0];
                    #pragma unroll
                    for (int mt = 1; mt < 4; ++mt)
                        #pragma unroll
                        for (int r = 0; r < 4; ++r) m4[r] = fmaxf(m4[r], a[mt][r]);
                    float vm = fmaxf(fmaxf(m4[0], m4[1]), fmaxf(m4[2], m4[3]));
                    vm = fmaxf(vm, __shfl_xor(vm, 16));
                    vm = fmaxf(vm, __shfl_xor(vm, 32));
                    vm *= sc2;
                    // T13 defer-max: only rescale when the max actually grows.
                    if (__any(vm > m_i[nf] + 8.0f)) {
                        float mnew = fmaxf(m_i[nf], vm);
                        float alpha = exp2f(m_i[nf] - mnew);
                        m_i[nf] = mnew;
                        l_i[nf] *= alpha;
                        #pragma unroll
                        for (int dt = 0; dt < 8; ++dt)
                            #pragma unroll
                            for (int r = 0; r < 4; ++r) o[nf][dt][r] *= alpha;
                    }
                    float mi = m_i[nf];
                    float ps = 0.0f;
                    #pragma unroll
                    for (int mt = 0; mt < 4; ++mt) {
                        unsigned short pk[4];
                        #pragma unroll
                        for (int r = 0; r < 4; ++r) {
                            float pv = exp2f(fmaf(a[mt][r], sc2, -mi));
                            ps += pv;
                            pk[r] = f2bu(pv);
                        }
                        *(uint2*)((unsigned short*)Pw + (nf * 16 + lr) * 72 + mt * 16 + lq * 4) =
                            *(uint2*)pk;
                    }
                    ps += __shfl_xor(ps, 16);
                    ps += __shfl_xor(ps, 32);
                    l_i[nf] += ps;
                }
                // in-wave LDS RAW
                __asm__ volatile("s_waitcnt lgkmcnt(0)" ::: "memory");
                bf16x8 ptf[2][2];
                #pragma unroll
                for (int nf = 0; nf < 2; ++nf)
                    #pragma unroll
                    for (int kt = 0; kt < 2; ++kt)
                        ptf[nf][kt] = *(const bf16x8*)(Pw + (nf * 16 + lr) * 72 + kt * 32 + lq * 8);
                // ---- O^T += V^T P: 32 MFMAs ----
                __builtin_amdgcn_s_setprio(1);
                #pragma unroll
                for (int kt = 0; kt < 2; ++kt)
                    #pragma unroll
                    for (int dt = 0; dt < 8; ++dt) {
                        o[0][dt] = MFMA16(vf[kt][dt], ptf[0][kt], o[0][dt]);
                        o[1][dt] = MFMA16(vf[kt][dt], ptf[1][kt], o[1][dt]);
                    }
                __builtin_amdgcn_s_setprio(0);
            }
            __syncthreads();    // drains vmcnt: stage(t+1) complete; Ks safe
            par ^= 1;
        }

        // ---- epilogue: O^T -> O via per-wave LDS transpose, partial store ----
        #pragma unroll
        for (int nf = 0; nf < 2; ++nf) {
            float l = l_i[nf];
            float wsc = (l > 0.0f) ? (1.0f / l) : 0.0f;
            float sst = (l > 0.0f) ? (m_i[nf] + log2f(l)) : -1e30f;
            __asm__ volatile("s_waitcnt lgkmcnt(0)" ::: "memory");
            #pragma unroll
            for (int dt = 0; dt < 8; ++dt) {
                unsigned short pk[4];
                #pragma unroll
                for (int r = 0; r < 4; ++r) pk[r] = f2bu(o[nf][dt][r] * wsc);
                *(uint2*)((unsigned short*)Pw + lr * 136 + dt * 16 + lq * 4) = *(uint2*)pk;
            }
            __asm__ volatile("s_waitcnt lgkmcnt(0)" ::: "memory");
            int ql = lane >> 2, cs = (lane & 3) * 32;
            int qrow = qw + nf * 16 + ql;
            uint4 d[4];
            #pragma unroll
            for (int k = 0; k < 4; ++k)
                d[k] = *(const uint4*)(Pw + ql * 136 + cs + k * 8);
            bf16* dst = (half ? opart : attn_out) +
                        (size_t)(b * 2048 + qrow) * 2048 + h * 128 + cs;
            #pragma unroll
            for (int k = 0; k < 4; ++k) *(uint4*)(dst + k * 8) = d[k];
            if (lane < 16) {
                int q2 = qw + nf * 16 + lane;
                mlbuf[((size_t)(b * 2048 + q2) * 16 + h) * 2 + half] = sst;
            }
        }
    }
#undef STAGE_K
}

// ---------------------------------------------------------------------------
// Merge the two key-chunk partials for every q row. s = m + log2(l) per chunk
// (log2 domain); partials are already normalized by their own l.
// ---------------------------------------------------------------------------
__global__ void attn_merge(const bf16* __restrict__ opart,
                           const float* __restrict__ mlbuf,
                           bf16* __restrict__ attn_out) {
    int bs = blockIdx.x;            // b*2048 + s
    int h = blockIdx.y * 2 + threadIdx.y;
    int tx = threadIdx.x;
    const float* mlp = mlbuf + ((size_t)bs * 16 + h) * 2;
    float s0 = mlp[0], s1 = mlp[1];
    size_t off = (size_t)bs * 2048 + h * 128 + tx;
    float o0 = __bfloat162float(attn_out[off]);
    float o1 = __bfloat162float(opart[off]);
    float m = fmaxf(s0, s1);
    float w0 = exp2f(s0 - m);
    float w1 = exp2f(s1 - m);
    float v = (o0 * w0 + o1 * w1) / (w0 + w1);
    attn_out[off] = __float2bfloat16(v);
}

// ---------------------------------------------------------------------------
extern "C" void kernel_launch(void* const* d_in, const int* in_sizes, int n_in,
                              void* d_out, int out_size, void* d_ws, size_t ws_size,
                              hipStream_t stream) {
    const float* x    = (const float*)d_in[0];
    const float* Wq   = (const float*)d_in[1];
    const float* Wdkv = (const float*)d_in[2];
    const float* Wkr  = (const float*)d_in[3];
    const float* Wukv = (const float*)d_in[4];
    const float* Wo   = (const float*)d_in[5];
    float* out = (float*)d_out;

    // Workspace layout (98,041,856 bytes), time-sliced aliasing.
    char* ws = (char*)d_ws;
    bf16* XW       = (bf16*)(ws);
    bf16* kbuf     = (bf16*)(ws + 30408704);
    bf16* vT       = (bf16*)(ws + 47185920);
    bf16* attn_out = (bf16*)(ws + 63963136);
    bf16* opart    = (bf16*)(ws + 80740352);
    float* mlbuf   = (float*)(ws + 97517568);   // 4096*16*2 floats = 512KB
    bf16* xb       = (bf16*)(ws + 30408704);  // alias kbuf
    bf16* WcatT    = (bf16*)(ws + 47185920);  // alias vT
    bf16* WukvT    = (bf16*)(ws + 63963136);  // alias attn_out
    bf16* WoT      = (bf16*)(ws + 47185920);  // alias vT (after attn)

    dim3 tb(32, 8);
    cvt_fp32_bf16<<<8192, 256, 0, stream>>>(x, xb);
    wtrans<<<dim3(96, 64), tb, 0, stream>>>(Wq, WcatT, 2048, 3072);
    wtrans<<<dim3(2, 64), tb, 0, stream>>>(Wkr, WcatT + (size_t)3072 * 2048, 2048, 64);
    wtrans<<<dim3(16, 64), tb, 0, stream>>>(Wdkv, WcatT + (size_t)3136 * 2048, 2048, 512);
    zerofill<<<512, 256, 0, stream>>>(WcatT + (size_t)3648 * 2048);
    wtrans<<<dim3(128, 16), tb, 0, stream>>>(Wukv, WukvT, 512, 4096);

    gemm_bt<bf16><<<dim3(29, 32), 256, 0, stream>>>(xb, 2048, WcatT, 2048, XW, 3712, 2048);
    rope_kernel<<<dim3(17, 1024), dim3(64, 4), 0, stream>>>(XW);
    gemm_kv<<<dim3(32, 32), 256, 0, stream>>>(XW + 3136, 3712, WukvT, 512, kbuf, vT, 512);
    attn_kernel<<<dim3(512), 256, 0, stream>>>(XW, kbuf, vT, attn_out, opart, mlbuf);
    attn_merge<<<dim3(4096, 8), dim3(128, 2), 0, stream>>>(opart, mlbuf, attn_out);
    wtrans<<<dim3(64, 64), tb, 0, stream>>>(Wo, WoT, 2048, 2048);
    gemm_bt<float><<<dim3(16, 32), 256, 0, stream>>>(attn_out, 2048, WoT, 2048, out, 2048, 2048);
}

// Round 4
// 471.781 us; speedup vs baseline: 1.2903x; 1.2903x over previous
//
#include <hip/hip_runtime.h>
#include <hip/hip_bf16.h>

using bf16 = __hip_bfloat16;
typedef __bf16 bf16x8 __attribute__((ext_vector_type(8)));
typedef float f32x4 __attribute__((ext_vector_type(4)));

#define MFMA16(A, B, C) __builtin_amdgcn_mfma_f32_16x16x32_bf16((A), (B), (C), 0, 0, 0)

__device__ __forceinline__ void store_elem(bf16* p, float v) { *p = __float2bfloat16(v); }
__device__ __forceinline__ void store_elem(float* p, float v) { *p = v; }

__device__ __forceinline__ unsigned short f2bu(float x) {
    bf16 t = __float2bfloat16(x);
    return *(unsigned short*)&t;
}

// async global->LDS 16B per lane; LDS dest = wave-uniform base + lane*16.
__device__ __forceinline__ void async_cp16(const bf16* g, bf16* l) {
    __builtin_amdgcn_global_load_lds(
        (const __attribute__((address_space(1))) void*)g,
        (__attribute__((address_space(3))) void*)l, 16, 0, 0);
}

// ---------------------------------------------------------------------------
__global__ void cvt_fp32_bf16(const float* __restrict__ src, bf16* __restrict__ dst) {
    int i = (blockIdx.x * 256 + threadIdx.x) * 4;
    float4 v = *(const float4*)(src + i);
    bf16 o[4] = {__float2bfloat16(v.x), __float2bfloat16(v.y),
                 __float2bfloat16(v.z), __float2bfloat16(v.w)};
    *(uint2*)(dst + i) = *(const uint2*)o;
}

// ---------------------------------------------------------------------------
__global__ void wtrans(const float* __restrict__ src, bf16* __restrict__ dst,
                       int K, int N) {
    __shared__ bf16 t[32][33];
    int n0 = blockIdx.x * 32, k0 = blockIdx.y * 32;
    #pragma unroll
    for (int i = 0; i < 4; ++i) {
        int r = threadIdx.y + i * 8;
        t[r][threadIdx.x] = __float2bfloat16(src[(size_t)(k0 + r) * N + n0 + threadIdx.x]);
    }
    __syncthreads();
    #pragma unroll
    for (int i = 0; i < 4; ++i) {
        int r = threadIdx.y + i * 8;
        dst[(size_t)(n0 + r) * K + k0 + threadIdx.x] = t[threadIdx.x][r];
    }
}

__global__ void zerofill(bf16* __restrict__ p) {
    p[blockIdx.x * 256 + threadIdx.x] = __float2bfloat16(0.0f);
}

// ---------------------------------------------------------------------------
// GEMM: C[M][N] = A[M][K] @ Bt[N][K]^T. global_load_lds staging (m97 pattern).
// ---------------------------------------------------------------------------
template <typename CT>
__global__ __launch_bounds__(256) void gemm_bt(
    const bf16* __restrict__ A, int lda,
    const bf16* __restrict__ Bt, int ldb,
    CT* __restrict__ C, int ldc, int K) {
    __shared__ bf16 As[128 * 32];
    __shared__ bf16 Bs[128 * 32];
    const int m0 = blockIdx.y * 128;
    const int n0 = blockIdx.x * 128;
    const int tid = threadIdx.x;
    const int lane = tid & 63;
    const int wave = tid >> 6;
    const int wm = (wave >> 1) * 64;
    const int wn = (wave & 1) * 64;
    const int lr = lane & 15;
    const int lq = lane >> 4;
    const int sr = tid >> 2;
    const int sc = (tid & 3) * 8;
    const int wbase = wave * 512;

    f32x4 acc[4][4] = {};

    for (int k0 = 0; k0 < K; k0 += 32) {
        __syncthreads();
        async_cp16(A + (size_t)(m0 + sr) * lda + k0 + sc, As + wbase);
        async_cp16(A + (size_t)(m0 + sr + 64) * lda + k0 + sc, As + 2048 + wbase);
        async_cp16(Bt + (size_t)(n0 + sr) * ldb + k0 + sc, Bs + wbase);
        async_cp16(Bt + (size_t)(n0 + sr + 64) * ldb + k0 + sc, Bs + 2048 + wbase);
        __syncthreads();
        bf16x8 af[4], bfr[4];
        #pragma unroll
        for (int t = 0; t < 4; ++t) {
            af[t]  = *(const bf16x8*)(As + (wm + t * 16 + lr) * 32 + lq * 8);
            bfr[t] = *(const bf16x8*)(Bs + (wn + t * 16 + lr) * 32 + lq * 8);
        }
        #pragma unroll
        for (int mt = 0; mt < 4; ++mt)
            #pragma unroll
            for (int nt = 0; nt < 4; ++nt)
                acc[mt][nt] = MFMA16(af[mt], bfr[nt], acc[mt][nt]);
    }
    #pragma unroll
    for (int mt = 0; mt < 4; ++mt)
        #pragma unroll
        for (int nt = 0; nt < 4; ++nt)
            #pragma unroll
            for (int r = 0; r < 4; ++r) {
                int row = m0 + wm + mt * 16 + lq * 4 + r;
                int col = n0 + wn + nt * 16 + lr;
                store_elem(C + (size_t)row * ldc + col, acc[mt][nt][r]);
            }
}

// ---------------------------------------------------------------------------
// kv GEMM, split epilogue: k_nope -> kbuf, v -> vT (transposed). grid (32,32).
// ---------------------------------------------------------------------------
__global__ __launch_bounds__(256) void gemm_kv(
    const bf16* __restrict__ A, int lda,
    const bf16* __restrict__ Bt, int ldb,
    bf16* __restrict__ kbuf, bf16* __restrict__ vT, int K) {
    __shared__ bf16 As[128 * 32];
    __shared__ bf16 Bs[128 * 32];
    const int m0 = blockIdx.y * 128;
    const int n0 = blockIdx.x * 128;
    const int tid = threadIdx.x;
    const int lane = tid & 63;
    const int wave = tid >> 6;
    const int wm = (wave >> 1) * 64;
    const int wn = (wave & 1) * 64;
    const int lr = lane & 15;
    const int lq = lane >> 4;
    const int sr = tid >> 2;
    const int sc = (tid & 3) * 8;
    const int wbase = wave * 512;

    f32x4 acc[4][4] = {};

    for (int k0 = 0; k0 < K; k0 += 32) {
        __syncthreads();
        async_cp16(A + (size_t)(m0 + sr) * lda + k0 + sc, As + wbase);
        async_cp16(A + (size_t)(m0 + sr + 64) * lda + k0 + sc, As + 2048 + wbase);
        async_cp16(Bt + (size_t)(n0 + sr) * ldb + k0 + sc, Bs + wbase);
        async_cp16(Bt + (size_t)(n0 + sr + 64) * ldb + k0 + sc, Bs + 2048 + wbase);
        __syncthreads();
        bf16x8 af[4], bfr[4];
        #pragma unroll
        for (int t = 0; t < 4; ++t) {
            af[t]  = *(const bf16x8*)(As + (wm + t * 16 + lr) * 32 + lq * 8);
            bfr[t] = *(const bf16x8*)(Bs + (wn + t * 16 + lr) * 32 + lq * 8);
        }
        #pragma unroll
        for (int mt = 0; mt < 4; ++mt)
            #pragma unroll
            for (int nt = 0; nt < 4; ++nt)
                acc[mt][nt] = MFMA16(af[mt], bfr[nt], acc[mt][nt]);
    }
    #pragma unroll
    for (int mt = 0; mt < 4; ++mt)
        #pragma unroll
        for (int nt = 0; nt < 4; ++nt) {
            int colbase = n0 + wn + nt * 16;
            int h = colbase >> 8;
            int rr = (colbase & 255) + lr;
            #pragma unroll
            for (int r = 0; r < 4; ++r) {
                int row = m0 + wm + mt * 16 + lq * 4 + r;
                bf16 val = __float2bfloat16(acc[mt][nt][r]);
                if (rr < 128) {
                    kbuf[(size_t)row * 2048 + h * 128 + rr] = val;
                } else {
                    int dv = rr - 128;
                    int b = row >> 11, s = row & 2047;
                    vT[((size_t)((b * 16 + h) * 128 + dv)) * 2048 + s] = val;
                }
            }
        }
}

// ---------------------------------------------------------------------------
__global__ void rope_kernel(bf16* __restrict__ XW) {
    int v = blockIdx.x;
    int row = blockIdx.y * 4 + threadIdx.y;
    int i = threadIdx.x;
    int s = row & 2047;
    int cbase = (v < 16) ? v * 192 + 128 : 3072;
    size_t base = (size_t)row * 3712 + cbase;
    float xi = __bfloat162float(XW[base + i]);
    float xp = __shfl_xor(xi, 32);
    int j = i & 31;
    float inv = exp2f(-(float)j * (13.287712379549449f / 32.0f));
    float ang = (float)s * inv;
    float c = cosf(ang), sn = sinf(ang);
    float res = (i < 32) ? (xi * c - xp * sn) : (xi * c + xp * sn);
    XW[base + i] = __float2bfloat16(res);
}

// ---------------------------------------------------------------------------
// Flash attention R4: K AND V block-cooperatively staged via global_load_lds.
//
// R3 post-mortem: holding vf[2][8] (64 VGPR) + rf at the compiler's hard
// 128-VGPR ceiling caused per-tile scratch spills (~230MB extra HBM reads
// AND writes -> memory-bound at 240us). Fix: V moves to LDS staging (zero
// VGPRs in flight), rope stays in registers (only 16). Live set ~110 VGPR.
//
// Decomposition (unchanged, verified): block = (bh, pair (U,15-U), key
// half); every block = exactly 17 tiles of KVBLK=64. 512 blocks x 4 waves.
//
// Per tile: barrier A (staging drained; Vs free) -> rope reg-loads ->
// stage V(t) -> stage K(t+1) -> S^T+softmax -> barrier B (compiler vmcnt(0)
// drain lands after ~700cy of compute) -> PV from Vs. No hand vmcnt.
//
// Ks and Vs are source-pre-swizzled (chunk ^ (row&7), rule 21): linear LDS
// dest, XOR'd per-lane global source, XOR'd read offset -> minimal bank
// load on ds_read_b128. LDS 66.4KB -> 2 blocks/CU, 8 waves/CU, 1 round.
// ---------------------------------------------------------------------------
__global__ __launch_bounds__(256, 2) void attn_kernel(
    const bf16* __restrict__ XW, const bf16* __restrict__ kbuf,
    const bf16* __restrict__ vT, bf16* __restrict__ attn_out,
    bf16* __restrict__ opart, float* __restrict__ mlbuf) {
    const int bid = blockIdx.x;
    const int half = bid >> 8;          // key-chunk index
    const int rem = bid & 255;
    const int bh = rem & 31;            // bid%8 == bh%8 -> XCD clustering
    const int p = rem >> 5;             // big-unit pair in [0,8)
    const int b = bh >> 4, h = bh & 15;
    const int tid = threadIdx.x;
    const int wave = tid >> 6;
    const int lane = tid & 63;
    const int lr = lane & 15, lq = lane >> 4;

    __shared__ bf16 Ks[2][64 * 128];    // K-nope tile, swizzled, dbuf (32KB)
    __shared__ bf16 Vs[128 * 64];       // V^T tile, swizzled, single (16KB)
    __shared__ bf16 Pm[4 * 32 * 72];    // per-wave 32x72 P; 16x136 Tr epilogue
    bf16* Pw = Pm + wave * (32 * 72);

    const bf16* xwb = XW + (size_t)b * 2048 * 3712;
    const bf16* kb  = kbuf + (size_t)b * 2048 * 2048 + h * 128;
    const bf16* rp  = xwb + 3072;       // k_rope columns
    const bf16* vTb = vT + (size_t)bh * 128 * 2048;

    const float sc2 = 0.07216878364870323f * 1.4426950408889634f;  // scale*log2e

    // K staging: 16 instrs/tile (4/wave); instr i covers rows i*4..i*4+3
    // (256B = 16 chunks each). Lane l: row r = i*4+(l>>4), dest chunk l&15
    // holds source chunk (l&15)^(r&7).
    const int s_rsub = lane >> 4;
    const int s_j    = lane & 15;
#define STAGE_K(N0, BUF) do {                                                  \
        _Pragma("unroll")                                                      \
        for (int k_ = 0; k_ < 4; ++k_) {                                       \
            int i_ = wave * 4 + k_;                                            \
            int r_ = i_ * 4 + s_rsub;                                          \
            int j_ = s_j ^ (r_ & 7);                                           \
            async_cp16(kb + (size_t)((N0) + r_) * 2048 + j_ * 8,               \
                       (BUF) + i_ * 512);                                      \
        }                                                                      \
    } while (0)

    // V staging: 16 instrs/tile (4/wave); instr i covers rows i*8..i*8+7
    // (128B = 8 chunks each). Lane l: row r = i*8+(l>>3), dest chunk l&7
    // holds source chunk (l&7)^(r&7).
#define STAGE_V(N0) do {                                                       \
        _Pragma("unroll")                                                      \
        for (int k_ = 0; k_ < 4; ++k_) {                                       \
            int i_ = wave * 4 + k_;                                            \
            int r_ = i_ * 8 + (lane >> 3);                                     \
            int j_ = (lane & 7) ^ (r_ & 7);                                    \
            async_cp16(vTb + (size_t)r_ * 2048 + (N0) + j_ * 8,                \
                       Vs + i_ * 512);                                         \
        }                                                                      \
    } while (0)

    // Read-side swizzled 16B-chunk offsets (elements):
    // Ks: row = mt*16+lr, want chunk c*4+lq. Vs: row = dt*16+lr, chunk kt*4+lq.
    const int rs = lr & 7;
    int koff[4];
    #pragma unroll
    for (int c = 0; c < 4; ++c) koff[c] = ((c * 4 + lq) ^ rs) * 8;
    int voff[2];
    voff[0] = (lq ^ rs) * 8;
    voff[1] = ((4 + lq) ^ rs) * 8;

    #pragma unroll 1
    for (int ph = 0; ph < 2; ++ph) {
        const int u = ph ? (15 - p) : p;       // big unit in [0,16)
        const int qw = u * 128 + wave * 32;    // this wave's first q row
        const int hnt = u + 1;                 // tiles per half
        const int t0 = half ? hnt : 0;
        const int t1 = half ? (2 * u + 2) : hnt;

        // Q B-frags: [n=q(lane&15)][k=lq*8..], 2 nf groups x 6 feature chunks
        bf16x8 qf[2][6];
        #pragma unroll
        for (int nf = 0; nf < 2; ++nf) {
            size_t ro = (size_t)(qw + nf * 16 + lr) * 3712 + h * 192;
            #pragma unroll
            for (int c = 0; c < 6; ++c)
                qf[nf][c] = *(const bf16x8*)(xwb + ro + c * 32 + lq * 8);
        }

        f32x4 o[2][8] = {};      // O^T: [nf][dt], col=q, row=dv
        float m_i[2], l_i[2];
        m_i[0] = m_i[1] = -1e30f;
        l_i[0] = l_i[1] = 0.0f;

        // prologue: stage first K tile (prior-ph Ks reads all completed
        // before the prior ph's last mid-tile barrier)
        STAGE_K(t0 * 64, Ks[0]);
        int par = 0;

        for (int t = t0; t < t1; ++t) {
            const int n0 = t * 64;
            __syncthreads();    // A: staging drained (Ks[par] ready, Vs free)

            // rope reg-loads FIRST: their implicit wait then leaves the
            // stage instrs (issued after) still in flight.
            bf16x8 rf[2][4];
            #pragma unroll
            for (int c = 0; c < 2; ++c)
                #pragma unroll
                for (int mt = 0; mt < 4; ++mt)
                    rf[c][mt] = *(const bf16x8*)(rp + (size_t)(n0 + mt * 16 + lr) * 3712 + c * 32 + lq * 8);

            STAGE_V(n0);
            if (t + 1 < t1) STAGE_K((t + 1) * 64, Ks[par ^ 1]);

            if (n0 < qw + 32) {  // wave-uniform: skip fully-masked tiles
                // ---- S^T = K Q^T: 16 LDS + 8 reg frags, 48 MFMAs ----
                const bf16* Kc = Ks[par];
                f32x4 st[4][2] = {};   // [mt(key)][nf(q)]
                __builtin_amdgcn_s_setprio(1);
                #pragma unroll
                for (int c = 0; c < 4; ++c) {
                    #pragma unroll
                    for (int mt = 0; mt < 4; ++mt) {
                        bf16x8 kf = *(const bf16x8*)(Kc + (mt * 16 + lr) * 128 + koff[c]);
                        st[mt][0] = MFMA16(kf, qf[0][c], st[mt][0]);
                        st[mt][1] = MFMA16(kf, qf[1][c], st[mt][1]);
                    }
                }
                #pragma unroll
                for (int c = 0; c < 2; ++c) {
                    #pragma unroll
                    for (int mt = 0; mt < 4; ++mt) {
                        st[mt][0] = MFMA16(rf[c][mt], qf[0][c + 4], st[mt][0]);
                        st[mt][1] = MFMA16(rf[c][mt], qf[1][c + 4], st[mt][1]);
                    }
                }
                __builtin_amdgcn_s_setprio(0);

                // ---- online softmax, raw-domain max, fma-folded scale ----
                #pragma unroll
                for (int nf = 0; nf < 2; ++nf) {
                    int q = qw + nf * 16 + lr;
                    f32x4 a[4];
                    #pragma unroll
                    for (int mt = 0; mt < 4; ++mt) a[mt] = st[mt][nf];
                    if (n0 + 63 > qw + nf * 16) {   // diagonal tile only
                        #pragma unroll
                        for (int mt = 0; mt < 4; ++mt)
                            #pragma unroll
                            for (int r = 0; r < 4; ++r) {
                                int kid = n0 + mt * 16 + lq * 4 + r;
                                if (kid > q) a[mt][r] = -1e30f;
                            }
                    }
                    f32x4 m4 = a[0];
                    #pragma unroll
                    for (int mt = 1; mt < 4; ++mt)
                        #pragma unroll
                        for (int r = 0; r < 4; ++r) m4[r] = fmaxf(m4[r], a[mt][r]);
                    float vm = fmaxf(fmaxf(m4[0], m4[1]), fmaxf(m4[2], m4[3]));
                    vm = fmaxf(vm, __shfl_xor(vm, 16));
                    vm = fmaxf(vm, __shfl_xor(vm, 32));
                    vm *= sc2;
                    // T13 defer-max: only rescale when the max actually grows.
                    if (__any(vm > m_i[nf] + 8.0f)) {
                        float mnew = fmaxf(m_i[nf], vm);
                        float alpha = exp2f(m_i[nf] - mnew);
                        m_i[nf] = mnew;
                        l_i[nf] *= alpha;
                        #pragma unroll
                        for (int dt = 0; dt < 8; ++dt)
                            #pragma unroll
                            for (int r = 0; r < 4; ++r) o[nf][dt][r] *= alpha;
                    }
                    float mi = m_i[nf];
                    float ps = 0.0f;
                    #pragma unroll
                    for (int mt = 0; mt < 4; ++mt) {
                        unsigned short pk[4];
                        #pragma unroll
                        for (int r = 0; r < 4; ++r) {
                            float pv = exp2f(fmaf(a[mt][r], sc2, -mi));
                            ps += pv;
                            pk[r] = f2bu(pv);
                        }
                        *(uint2*)((unsigned short*)Pw + (nf * 16 + lr) * 72 + mt * 16 + lq * 4) =
                            *(uint2*)pk;
                    }
                    ps += __shfl_xor(ps, 16);
                    ps += __shfl_xor(ps, 32);
                    l_i[nf] += ps;
                }
            }

            __syncthreads();    // B: V(t) staged (and K(t+1), early); P visible

            if (n0 < qw + 32) {
                bf16x8 ptf[2][2];
                #pragma unroll
                for (int nf = 0; nf < 2; ++nf)
                    #pragma unroll
                    for (int kt = 0; kt < 2; ++kt)
                        ptf[nf][kt] = *(const bf16x8*)(Pw + (nf * 16 + lr) * 72 + kt * 32 + lq * 8);
                // ---- O^T += V^T P: 16 LDS reads, 32 MFMAs ----
                __builtin_amdgcn_s_setprio(1);
                #pragma unroll
                for (int kt = 0; kt < 2; ++kt)
                    #pragma unroll
                    for (int dt = 0; dt < 8; ++dt) {
                        bf16x8 vfr = *(const bf16x8*)(Vs + (dt * 16 + lr) * 64 + voff[kt]);
                        o[0][dt] = MFMA16(vfr, ptf[0][kt], o[0][dt]);
                        o[1][dt] = MFMA16(vfr, ptf[1][kt], o[1][dt]);
                    }
                __builtin_amdgcn_s_setprio(0);
            }
            par ^= 1;
        }

        // ---- epilogue: O^T -> O via per-wave LDS transpose, partial store ----
        #pragma unroll
        for (int nf = 0; nf < 2; ++nf) {
            float l = l_i[nf];
            float wsc = (l > 0.0f) ? (1.0f / l) : 0.0f;
            float sst = (l > 0.0f) ? (m_i[nf] + log2f(l)) : -1e30f;
            __asm__ volatile("s_waitcnt lgkmcnt(0)" ::: "memory");
            #pragma unroll
            for (int dt = 0; dt < 8; ++dt) {
                unsigned short pk[4];
                #pragma unroll
                for (int r = 0; r < 4; ++r) pk[r] = f2bu(o[nf][dt][r] * wsc);
                *(uint2*)((unsigned short*)Pw + lr * 136 + dt * 16 + lq * 4) = *(uint2*)pk;
            }
            __asm__ volatile("s_waitcnt lgkmcnt(0)" ::: "memory");
            int ql = lane >> 2, cs = (lane & 3) * 32;
            int qrow = qw + nf * 16 + ql;
            uint4 d[4];
            #pragma unroll
            for (int k = 0; k < 4; ++k)
                d[k] = *(const uint4*)(Pw + ql * 136 + cs + k * 8);
            bf16* dst = (half ? opart : attn_out) +
                        (size_t)(b * 2048 + qrow) * 2048 + h * 128 + cs;
            #pragma unroll
            for (int k = 0; k < 4; ++k) *(uint4*)(dst + k * 8) = d[k];
            if (lane < 16) {
                int q2 = qw + nf * 16 + lane;
                mlbuf[((size_t)(b * 2048 + q2) * 16 + h) * 2 + half] = sst;
            }
        }
    }
#undef STAGE_K
#undef STAGE_V
}

// ---------------------------------------------------------------------------
// Merge the two key-chunk partials for every q row. s = m + log2(l) per chunk
// (log2 domain); partials are already normalized by their own l.
// ---------------------------------------------------------------------------
__global__ void attn_merge(const bf16* __restrict__ opart,
                           const float* __restrict__ mlbuf,
                           bf16* __restrict__ attn_out) {
    int bs = blockIdx.x;            // b*2048 + s
    int h = blockIdx.y * 2 + threadIdx.y;
    int tx = threadIdx.x;
    const float* mlp = mlbuf + ((size_t)bs * 16 + h) * 2;
    float s0 = mlp[0], s1 = mlp[1];
    size_t off = (size_t)bs * 2048 + h * 128 + tx;
    float o0 = __bfloat162float(attn_out[off]);
    float o1 = __bfloat162float(opart[off]);
    float m = fmaxf(s0, s1);
    float w0 = exp2f(s0 - m);
    float w1 = exp2f(s1 - m);
    float v = (o0 * w0 + o1 * w1) / (w0 + w1);
    attn_out[off] = __float2bfloat16(v);
}

// ---------------------------------------------------------------------------
extern "C" void kernel_launch(void* const* d_in, const int* in_sizes, int n_in,
                              void* d_out, int out_size, void* d_ws, size_t ws_size,
                              hipStream_t stream) {
    const float* x    = (const float*)d_in[0];
    const float* Wq   = (const float*)d_in[1];
    const float* Wdkv = (const float*)d_in[2];
    const float* Wkr  = (const float*)d_in[3];
    const float* Wukv = (const float*)d_in[4];
    const float* Wo   = (const float*)d_in[5];
    float* out = (float*)d_out;

    // Workspace layout (98,041,856 bytes), time-sliced aliasing.
    char* ws = (char*)d_ws;
    bf16* XW       = (bf16*)(ws);
    bf16* kbuf     = (bf16*)(ws + 30408704);
    bf16* vT       = (bf16*)(ws + 47185920);
    bf16* attn_out = (bf16*)(ws + 63963136);
    bf16* opart    = (bf16*)(ws + 80740352);
    float* mlbuf   = (float*)(ws + 97517568);   // 4096*16*2 floats = 512KB
    bf16* xb       = (bf16*)(ws + 30408704);  // alias kbuf
    bf16* WcatT    = (bf16*)(ws + 47185920);  // alias vT
    bf16* WukvT    = (bf16*)(ws + 63963136);  // alias attn_out
    bf16* WoT      = (bf16*)(ws + 47185920);  // alias vT (after attn)

    dim3 tb(32, 8);
    cvt_fp32_bf16<<<8192, 256, 0, stream>>>(x, xb);
    wtrans<<<dim3(96, 64), tb, 0, stream>>>(Wq, WcatT, 2048, 3072);
    wtrans<<<dim3(2, 64), tb, 0, stream>>>(Wkr, WcatT + (size_t)3072 * 2048, 2048, 64);
    wtrans<<<dim3(16, 64), tb, 0, stream>>>(Wdkv, WcatT + (size_t)3136 * 2048, 2048, 512);
    zerofill<<<512, 256, 0, stream>>>(WcatT + (size_t)3648 * 2048);
    wtrans<<<dim3(128, 16), tb, 0, stream>>>(Wukv, WukvT, 512, 4096);

    gemm_bt<bf16><<<dim3(29, 32), 256, 0, stream>>>(xb, 2048, WcatT, 2048, XW, 3712, 2048);
    rope_kernel<<<dim3(17, 1024), dim3(64, 4), 0, stream>>>(XW);
    gemm_kv<<<dim3(32, 32), 256, 0, stream>>>(XW + 3136, 3712, WukvT, 512, kbuf, vT, 512);
    attn_kernel<<<dim3(512), 256, 0, stream>>>(XW, kbuf, vT, attn_out, opart, mlbuf);
    attn_merge<<<dim3(4096, 8), dim3(128, 2), 0, stream>>>(opart, mlbuf, attn_out);
    wtrans<<<dim3(64, 64), tb, 0, stream>>>(Wo, WoT, 2048, 2048);
    gemm_bt<float><<<dim3(16, 32), 256, 0, stream>>>(attn_out, 2048, WoT, 2048, out, 2048, 2048);
}

// Round 5
// 457.458 us; speedup vs baseline: 1.3307x; 1.0313x over previous
//
#include <hip/hip_runtime.h>
#include <hip/hip_bf16.h>

using bf16 = __hip_bfloat16;
typedef __bf16 bf16x8 __attribute__((ext_vector_type(8)));
typedef float f32x4 __attribute__((ext_vector_type(4)));

#define MFMA16(A, B, C) __builtin_amdgcn_mfma_f32_16x16x32_bf16((A), (B), (C), 0, 0, 0)

__device__ __forceinline__ void store_elem(bf16* p, float v) { *p = __float2bfloat16(v); }
__device__ __forceinline__ void store_elem(float* p, float v) { *p = v; }

__device__ __forceinline__ unsigned short f2bu(float x) {
    bf16 t = __float2bfloat16(x);
    return *(unsigned short*)&t;
}

// async global->LDS 16B per lane; LDS dest = wave-uniform base + lane*16.
__device__ __forceinline__ void async_cp16(const bf16* g, bf16* l) {
    __builtin_amdgcn_global_load_lds(
        (const __attribute__((address_space(1))) void*)g,
        (__attribute__((address_space(3))) void*)l, 16, 0, 0);
}

// ---------------------------------------------------------------------------
__global__ void cvt_fp32_bf16(const float* __restrict__ src, bf16* __restrict__ dst) {
    int i = (blockIdx.x * 256 + threadIdx.x) * 4;
    float4 v = *(const float4*)(src + i);
    bf16 o[4] = {__float2bfloat16(v.x), __float2bfloat16(v.y),
                 __float2bfloat16(v.z), __float2bfloat16(v.w)};
    *(uint2*)(dst + i) = *(const uint2*)o;
}

// ---------------------------------------------------------------------------
__global__ void wtrans(const float* __restrict__ src, bf16* __restrict__ dst,
                       int K, int N) {
    __shared__ bf16 t[32][33];
    int n0 = blockIdx.x * 32, k0 = blockIdx.y * 32;
    #pragma unroll
    for (int i = 0; i < 4; ++i) {
        int r = threadIdx.y + i * 8;
        t[r][threadIdx.x] = __float2bfloat16(src[(size_t)(k0 + r) * N + n0 + threadIdx.x]);
    }
    __syncthreads();
    #pragma unroll
    for (int i = 0; i < 4; ++i) {
        int r = threadIdx.y + i * 8;
        dst[(size_t)(n0 + r) * K + k0 + threadIdx.x] = t[threadIdx.x][r];
    }
}

__global__ void zerofill(bf16* __restrict__ p) {
    p[blockIdx.x * 256 + threadIdx.x] = __float2bfloat16(0.0f);
}

// ---------------------------------------------------------------------------
// GEMM: C[M][N] = A[M][K] @ Bt[N][K]^T.
// R5: T3-minimum 2-phase (stage t+1 overlaps compute t, ONE barrier/K-step)
// + chunked bijective XCD swizzle (each XCD owns a contiguous flat range ->
// A row-panels fetched once per XCD instead of 8x). Grids must be %8==0
// (29x32=928, 32x32=1024, 16x32=512: all ok).
// ---------------------------------------------------------------------------
template <typename CT>
__global__ __launch_bounds__(256) void gemm_bt(
    const bf16* __restrict__ A, int lda,
    const bf16* __restrict__ Bt, int ldb,
    CT* __restrict__ C, int ldc, int K) {
    __shared__ bf16 As[2][128 * 32];
    __shared__ bf16 Bs[2][128 * 32];
    const int nwg = gridDim.x * gridDim.y;
    const int flat = blockIdx.y * gridDim.x + blockIdx.x;
    const int swz = (flat & 7) * (nwg >> 3) + (flat >> 3);
    const int m0 = (swz / gridDim.x) * 128;
    const int n0 = (swz % gridDim.x) * 128;
    const int tid = threadIdx.x;
    const int lane = tid & 63;
    const int wave = tid >> 6;
    const int wm = (wave >> 1) * 64;
    const int wn = (wave & 1) * 64;
    const int lr = lane & 15;
    const int lq = lane >> 4;
    const int sr = tid >> 2;
    const int sc = (tid & 3) * 8;
    const int wbase = wave * 512;

    f32x4 acc[4][4] = {};

#define G_STAGE(BUF, KO) do {                                                  \
        async_cp16(A + (size_t)(m0 + sr) * lda + (KO) + sc, As[BUF] + wbase);  \
        async_cp16(A + (size_t)(m0 + sr + 64) * lda + (KO) + sc,               \
                   As[BUF] + 2048 + wbase);                                    \
        async_cp16(Bt + (size_t)(n0 + sr) * ldb + (KO) + sc, Bs[BUF] + wbase); \
        async_cp16(Bt + (size_t)(n0 + sr + 64) * ldb + (KO) + sc,              \
                   Bs[BUF] + 2048 + wbase);                                    \
    } while (0)

    G_STAGE(0, 0);
    __syncthreads();          // buf0 staged (vmcnt drained at barrier)
    int cur = 0;
    for (int k0 = 0; k0 < K; k0 += 32) {
        if (k0 + 32 < K) G_STAGE(cur ^ 1, k0 + 32);   // overlap with compute
        bf16x8 af[4], bfr[4];
        #pragma unroll
        for (int t = 0; t < 4; ++t) {
            af[t]  = *(const bf16x8*)(As[cur] + (wm + t * 16 + lr) * 32 + lq * 8);
            bfr[t] = *(const bf16x8*)(Bs[cur] + (wn + t * 16 + lr) * 32 + lq * 8);
        }
        #pragma unroll
        for (int mt = 0; mt < 4; ++mt)
            #pragma unroll
            for (int nt = 0; nt < 4; ++nt)
                acc[mt][nt] = MFMA16(af[mt], bfr[nt], acc[mt][nt]);
        __syncthreads();      // next buffer staged; this buffer's reads done
        cur ^= 1;
    }
#undef G_STAGE
    #pragma unroll
    for (int mt = 0; mt < 4; ++mt)
        #pragma unroll
        for (int nt = 0; nt < 4; ++nt)
            #pragma unroll
            for (int r = 0; r < 4; ++r) {
                int row = m0 + wm + mt * 16 + lq * 4 + r;
                int col = n0 + wn + nt * 16 + lr;
                store_elem(C + (size_t)row * ldc + col, acc[mt][nt][r]);
            }
}

// ---------------------------------------------------------------------------
// kv GEMM, split epilogue: k_nope -> kbuf, v -> vT (transposed). grid (32,32).
// Same 2-phase + XCD swizzle as gemm_bt.
// ---------------------------------------------------------------------------
__global__ __launch_bounds__(256) void gemm_kv(
    const bf16* __restrict__ A, int lda,
    const bf16* __restrict__ Bt, int ldb,
    bf16* __restrict__ kbuf, bf16* __restrict__ vT, int K) {
    __shared__ bf16 As[2][128 * 32];
    __shared__ bf16 Bs[2][128 * 32];
    const int nwg = gridDim.x * gridDim.y;
    const int flat = blockIdx.y * gridDim.x + blockIdx.x;
    const int swz = (flat & 7) * (nwg >> 3) + (flat >> 3);
    const int m0 = (swz / gridDim.x) * 128;
    const int n0 = (swz % gridDim.x) * 128;
    const int tid = threadIdx.x;
    const int lane = tid & 63;
    const int wave = tid >> 6;
    const int wm = (wave >> 1) * 64;
    const int wn = (wave & 1) * 64;
    const int lr = lane & 15;
    const int lq = lane >> 4;
    const int sr = tid >> 2;
    const int sc = (tid & 3) * 8;
    const int wbase = wave * 512;

    f32x4 acc[4][4] = {};

#define G_STAGE(BUF, KO) do {                                                  \
        async_cp16(A + (size_t)(m0 + sr) * lda + (KO) + sc, As[BUF] + wbase);  \
        async_cp16(A + (size_t)(m0 + sr + 64) * lda + (KO) + sc,               \
                   As[BUF] + 2048 + wbase);                                    \
        async_cp16(Bt + (size_t)(n0 + sr) * ldb + (KO) + sc, Bs[BUF] + wbase); \
        async_cp16(Bt + (size_t)(n0 + sr + 64) * ldb + (KO) + sc,              \
                   Bs[BUF] + 2048 + wbase);                                    \
    } while (0)

    G_STAGE(0, 0);
    __syncthreads();
    int cur = 0;
    for (int k0 = 0; k0 < K; k0 += 32) {
        if (k0 + 32 < K) G_STAGE(cur ^ 1, k0 + 32);
        bf16x8 af[4], bfr[4];
        #pragma unroll
        for (int t = 0; t < 4; ++t) {
            af[t]  = *(const bf16x8*)(As[cur] + (wm + t * 16 + lr) * 32 + lq * 8);
            bfr[t] = *(const bf16x8*)(Bs[cur] + (wn + t * 16 + lr) * 32 + lq * 8);
        }
        #pragma unroll
        for (int mt = 0; mt < 4; ++mt)
            #pragma unroll
            for (int nt = 0; nt < 4; ++nt)
                acc[mt][nt] = MFMA16(af[mt], bfr[nt], acc[mt][nt]);
        __syncthreads();
        cur ^= 1;
    }
#undef G_STAGE
    #pragma unroll
    for (int mt = 0; mt < 4; ++mt)
        #pragma unroll
        for (int nt = 0; nt < 4; ++nt) {
            int colbase = n0 + wn + nt * 16;
            int h = colbase >> 8;
            int rr = (colbase & 255) + lr;
            #pragma unroll
            for (int r = 0; r < 4; ++r) {
                int row = m0 + wm + mt * 16 + lq * 4 + r;
                bf16 val = __float2bfloat16(acc[mt][nt][r]);
                if (rr < 128) {
                    kbuf[(size_t)row * 2048 + h * 128 + rr] = val;
                } else {
                    int dv = rr - 128;
                    int b = row >> 11, s = row & 2047;
                    vT[((size_t)((b * 16 + h) * 128 + dv)) * 2048 + s] = val;
                }
            }
        }
}

// ---------------------------------------------------------------------------
__global__ void rope_kernel(bf16* __restrict__ XW) {
    int v = blockIdx.x;
    int row = blockIdx.y * 4 + threadIdx.y;
    int i = threadIdx.x;
    int s = row & 2047;
    int cbase = (v < 16) ? v * 192 + 128 : 3072;
    size_t base = (size_t)row * 3712 + cbase;
    float xi = __bfloat162float(XW[base + i]);
    float xp = __shfl_xor(xi, 32);
    int j = i & 31;
    float inv = exp2f(-(float)j * (13.287712379549449f / 32.0f));
    float ang = (float)s * inv;
    float c = cosf(ang), sn = sinf(ang);
    float res = (i < 32) ? (xi * c - xp * sn) : (xi * c + xp * sn);
    XW[base + i] = __float2bfloat16(res);
}

// ---------------------------------------------------------------------------
// Flash attention R4 structure (kept): K AND V block-cooperatively staged via
// global_load_lds; rope in registers (16 VGPR); live set ~110 VGPR, no spill.
// Decomposition: block = (bh, pair (U,15-U), key half); every block = exactly
// 17 tiles of KVBLK=64. 512 blocks x 4 waves. Ks/Vs source-pre-swizzled
// (chunk ^ (row&7)). LDS 66.4KB -> 2 blocks/CU, 8 waves/CU, 1 round.
// ---------------------------------------------------------------------------
__global__ __launch_bounds__(256, 2) void attn_kernel(
    const bf16* __restrict__ XW, const bf16* __restrict__ kbuf,
    const bf16* __restrict__ vT, bf16* __restrict__ attn_out,
    bf16* __restrict__ opart, float* __restrict__ mlbuf) {
    const int bid = blockIdx.x;
    const int half = bid >> 8;          // key-chunk index
    const int rem = bid & 255;
    const int bh = rem & 31;            // bid%8 == bh%8 -> XCD clustering
    const int p = rem >> 5;             // big-unit pair in [0,8)
    const int b = bh >> 4, h = bh & 15;
    const int tid = threadIdx.x;
    const int wave = tid >> 6;
    const int lane = tid & 63;
    const int lr = lane & 15, lq = lane >> 4;

    __shared__ bf16 Ks[2][64 * 128];    // K-nope tile, swizzled, dbuf (32KB)
    __shared__ bf16 Vs[128 * 64];       // V^T tile, swizzled, single (16KB)
    __shared__ bf16 Pm[4 * 32 * 72];    // per-wave 32x72 P; 16x136 Tr epilogue
    bf16* Pw = Pm + wave * (32 * 72);

    const bf16* xwb = XW + (size_t)b * 2048 * 3712;
    const bf16* kb  = kbuf + (size_t)b * 2048 * 2048 + h * 128;
    const bf16* rp  = xwb + 3072;       // k_rope columns
    const bf16* vTb = vT + (size_t)bh * 128 * 2048;

    const float sc2 = 0.07216878364870323f * 1.4426950408889634f;  // scale*log2e

    const int s_rsub = lane >> 4;
    const int s_j    = lane & 15;
#define STAGE_K(N0, BUF) do {                                                  \
        _Pragma("unroll")                                                      \
        for (int k_ = 0; k_ < 4; ++k_) {                                       \
            int i_ = wave * 4 + k_;                                            \
            int r_ = i_ * 4 + s_rsub;                                          \
            int j_ = s_j ^ (r_ & 7);                                           \
            async_cp16(kb + (size_t)((N0) + r_) * 2048 + j_ * 8,               \
                       (BUF) + i_ * 512);                                      \
        }                                                                      \
    } while (0)

#define STAGE_V(N0) do {                                                       \
        _Pragma("unroll")                                                      \
        for (int k_ = 0; k_ < 4; ++k_) {                                       \
            int i_ = wave * 4 + k_;                                            \
            int r_ = i_ * 8 + (lane >> 3);                                     \
            int j_ = (lane & 7) ^ (r_ & 7);                                    \
            async_cp16(vTb + (size_t)r_ * 2048 + (N0) + j_ * 8,                \
                       Vs + i_ * 512);                                         \
        }                                                                      \
    } while (0)

    const int rs = lr & 7;
    int koff[4];
    #pragma unroll
    for (int c = 0; c < 4; ++c) koff[c] = ((c * 4 + lq) ^ rs) * 8;
    int voff[2];
    voff[0] = (lq ^ rs) * 8;
    voff[1] = ((4 + lq) ^ rs) * 8;

    #pragma unroll 1
    for (int ph = 0; ph < 2; ++ph) {
        const int u = ph ? (15 - p) : p;       // big unit in [0,16)
        const int qw = u * 128 + wave * 32;    // this wave's first q row
        const int hnt = u + 1;                 // tiles per half
        const int t0 = half ? hnt : 0;
        const int t1 = half ? (2 * u + 2) : hnt;

        // Q B-frags: [n=q(lane&15)][k=lq*8..], 2 nf groups x 6 feature chunks
        bf16x8 qf[2][6];
        #pragma unroll
        for (int nf = 0; nf < 2; ++nf) {
            size_t ro = (size_t)(qw + nf * 16 + lr) * 3712 + h * 192;
            #pragma unroll
            for (int c = 0; c < 6; ++c)
                qf[nf][c] = *(const bf16x8*)(xwb + ro + c * 32 + lq * 8);
        }

        f32x4 o[2][8] = {};      // O^T: [nf][dt], col=q, row=dv
        float m_i[2], l_i[2];
        m_i[0] = m_i[1] = -1e30f;
        l_i[0] = l_i[1] = 0.0f;

        STAGE_K(t0 * 64, Ks[0]);
        int par = 0;

        for (int t = t0; t < t1; ++t) {
            const int n0 = t * 64;
            __syncthreads();    // A: staging drained (Ks[par] ready, Vs free)

            bf16x8 rf[2][4];
            #pragma unroll
            for (int c = 0; c < 2; ++c)
                #pragma unroll
                for (int mt = 0; mt < 4; ++mt)
                    rf[c][mt] = *(const bf16x8*)(rp + (size_t)(n0 + mt * 16 + lr) * 3712 + c * 32 + lq * 8);

            STAGE_V(n0);
            if (t + 1 < t1) STAGE_K((t + 1) * 64, Ks[par ^ 1]);

            if (n0 < qw + 32) {  // wave-uniform: skip fully-masked tiles
                const bf16* Kc = Ks[par];
                f32x4 st[4][2] = {};   // [mt(key)][nf(q)]
                __builtin_amdgcn_s_setprio(1);
                #pragma unroll
                for (int c = 0; c < 4; ++c) {
                    #pragma unroll
                    for (int mt = 0; mt < 4; ++mt) {
                        bf16x8 kf = *(const bf16x8*)(Kc + (mt * 16 + lr) * 128 + koff[c]);
                        st[mt][0] = MFMA16(kf, qf[0][c], st[mt][0]);
                        st[mt][1] = MFMA16(kf, qf[1][c], st[mt][1]);
                    }
                }
                #pragma unroll
                for (int c = 0; c < 2; ++c) {
                    #pragma unroll
                    for (int mt = 0; mt < 4; ++mt) {
                        st[mt][0] = MFMA16(rf[c][mt], qf[0][c + 4], st[mt][0]);
                        st[mt][1] = MFMA16(rf[c][mt], qf[1][c + 4], st[mt][1]);
                    }
                }
                __builtin_amdgcn_s_setprio(0);

                #pragma unroll
                for (int nf = 0; nf < 2; ++nf) {
                    int q = qw + nf * 16 + lr;
                    f32x4 a[4];
                    #pragma unroll
                    for (int mt = 0; mt < 4; ++mt) a[mt] = st[mt][nf];
                    if (n0 + 63 > qw + nf * 16) {   // diagonal tile only
                        #pragma unroll
                        for (int mt = 0; mt < 4; ++mt)
                            #pragma unroll
                            for (int r = 0; r < 4; ++r) {
                                int kid = n0 + mt * 16 + lq * 4 + r;
                                if (kid > q) a[mt][r] = -1e30f;
                            }
                    }
                    f32x4 m4 = a[0];
                    #pragma unroll
                    for (int mt = 1; mt < 4; ++mt)
                        #pragma unroll
                        for (int r = 0; r < 4; ++r) m4[r] = fmaxf(m4[r], a[mt][r]);
                    float vm = fmaxf(fmaxf(m4[0], m4[1]), fmaxf(m4[2], m4[3]));
                    vm = fmaxf(vm, __shfl_xor(vm, 16));
                    vm = fmaxf(vm, __shfl_xor(vm, 32));
                    vm *= sc2;
                    // T13 defer-max: only rescale when the max actually grows.
                    if (__any(vm > m_i[nf] + 8.0f)) {
                        float mnew = fmaxf(m_i[nf], vm);
                        float alpha = exp2f(m_i[nf] - mnew);
                        m_i[nf] = mnew;
                        l_i[nf] *= alpha;
                        #pragma unroll
                        for (int dt = 0; dt < 8; ++dt)
                            #pragma unroll
                            for (int r = 0; r < 4; ++r) o[nf][dt][r] *= alpha;
                    }
                    float mi = m_i[nf];
                    float ps = 0.0f;
                    #pragma unroll
                    for (int mt = 0; mt < 4; ++mt) {
                        unsigned short pk[4];
                        #pragma unroll
                        for (int r = 0; r < 4; ++r) {
                            float pv = exp2f(fmaf(a[mt][r], sc2, -mi));
                            ps += pv;
                            pk[r] = f2bu(pv);
                        }
                        *(uint2*)((unsigned short*)Pw + (nf * 16 + lr) * 72 + mt * 16 + lq * 4) =
                            *(uint2*)pk;
                    }
                    ps += __shfl_xor(ps, 16);
                    ps += __shfl_xor(ps, 32);
                    l_i[nf] += ps;
                }
            }

            __syncthreads();    // B: V(t) staged (and K(t+1), early); P visible

            if (n0 < qw + 32) {
                bf16x8 ptf[2][2];
                #pragma unroll
                for (int nf = 0; nf < 2; ++nf)
                    #pragma unroll
                    for (int kt = 0; kt < 2; ++kt)
                        ptf[nf][kt] = *(const bf16x8*)(Pw + (nf * 16 + lr) * 72 + kt * 32 + lq * 8);
                __builtin_amdgcn_s_setprio(1);
                #pragma unroll
                for (int kt = 0; kt < 2; ++kt)
                    #pragma unroll
                    for (int dt = 0; dt < 8; ++dt) {
                        bf16x8 vfr = *(const bf16x8*)(Vs + (dt * 16 + lr) * 64 + voff[kt]);
                        o[0][dt] = MFMA16(vfr, ptf[0][kt], o[0][dt]);
                        o[1][dt] = MFMA16(vfr, ptf[1][kt], o[1][dt]);
                    }
                __builtin_amdgcn_s_setprio(0);
            }
            par ^= 1;
        }

        // ---- epilogue: O^T -> O via per-wave LDS transpose, partial store ----
        #pragma unroll
        for (int nf = 0; nf < 2; ++nf) {
            float l = l_i[nf];
            float wsc = (l > 0.0f) ? (1.0f / l) : 0.0f;
            float sst = (l > 0.0f) ? (m_i[nf] + log2f(l)) : -1e30f;
            __asm__ volatile("s_waitcnt lgkmcnt(0)" ::: "memory");
            #pragma unroll
            for (int dt = 0; dt < 8; ++dt) {
                unsigned short pk[4];
                #pragma unroll
                for (int r = 0; r < 4; ++r) pk[r] = f2bu(o[nf][dt][r] * wsc);
                *(uint2*)((unsigned short*)Pw + lr * 136 + dt * 16 + lq * 4) = *(uint2*)pk;
            }
            __asm__ volatile("s_waitcnt lgkmcnt(0)" ::: "memory");
            int ql = lane >> 2, cs = (lane & 3) * 32;
            int qrow = qw + nf * 16 + ql;
            uint4 d[4];
            #pragma unroll
            for (int k = 0; k < 4; ++k)
                d[k] = *(const uint4*)(Pw + ql * 136 + cs + k * 8);
            bf16* dst = (half ? opart : attn_out) +
                        (size_t)(b * 2048 + qrow) * 2048 + h * 128 + cs;
            #pragma unroll
            for (int k = 0; k < 4; ++k) *(uint4*)(dst + k * 8) = d[k];
            if (lane < 16) {
                int q2 = qw + nf * 16 + lane;
                mlbuf[((size_t)(b * 2048 + q2) * 16 + h) * 2 + half] = sst;
            }
        }
    }
#undef STAGE_K
#undef STAGE_V
}

// ---------------------------------------------------------------------------
// Merge the two key-chunk partials for every q row. s = m + log2(l) per chunk
// (log2 domain); partials are already normalized by their own l.
// ---------------------------------------------------------------------------
__global__ void attn_merge(const bf16* __restrict__ opart,
                           const float* __restrict__ mlbuf,
                           bf16* __restrict__ attn_out) {
    int bs = blockIdx.x;            // b*2048 + s
    int h = blockIdx.y * 2 + threadIdx.y;
    int tx = threadIdx.x;
    const float* mlp = mlbuf + ((size_t)bs * 16 + h) * 2;
    float s0 = mlp[0], s1 = mlp[1];
    size_t off = (size_t)bs * 2048 + h * 128 + tx;
    float o0 = __bfloat162float(attn_out[off]);
    float o1 = __bfloat162float(opart[off]);
    float m = fmaxf(s0, s1);
    float w0 = exp2f(s0 - m);
    float w1 = exp2f(s1 - m);
    float v = (o0 * w0 + o1 * w1) / (w0 + w1);
    attn_out[off] = __float2bfloat16(v);
}

// ---------------------------------------------------------------------------
extern "C" void kernel_launch(void* const* d_in, const int* in_sizes, int n_in,
                              void* d_out, int out_size, void* d_ws, size_t ws_size,
                              hipStream_t stream) {
    const float* x    = (const float*)d_in[0];
    const float* Wq   = (const float*)d_in[1];
    const float* Wdkv = (const float*)d_in[2];
    const float* Wkr  = (const float*)d_in[3];
    const float* Wukv = (const float*)d_in[4];
    const float* Wo   = (const float*)d_in[5];
    float* out = (float*)d_out;

    // Workspace layout (98,041,856 bytes), time-sliced aliasing.
    char* ws = (char*)d_ws;
    bf16* XW       = (bf16*)(ws);
    bf16* kbuf     = (bf16*)(ws + 30408704);
    bf16* vT       = (bf16*)(ws + 47185920);
    bf16* attn_out = (bf16*)(ws + 63963136);
    bf16* opart    = (bf16*)(ws + 80740352);
    float* mlbuf   = (float*)(ws + 97517568);   // 4096*16*2 floats = 512KB
    bf16* xb       = (bf16*)(ws + 30408704);  // alias kbuf
    bf16* WcatT    = (bf16*)(ws + 47185920);  // alias vT
    bf16* WukvT    = (bf16*)(ws + 63963136);  // alias attn_out
    bf16* WoT      = (bf16*)(ws + 47185920);  // alias vT (after attn)

    dim3 tb(32, 8);
    cvt_fp32_bf16<<<8192, 256, 0, stream>>>(x, xb);
    wtrans<<<dim3(96, 64), tb, 0, stream>>>(Wq, WcatT, 2048, 3072);
    wtrans<<<dim3(2, 64), tb, 0, stream>>>(Wkr, WcatT + (size_t)3072 * 2048, 2048, 64);
    wtrans<<<dim3(16, 64), tb, 0, stream>>>(Wdkv, WcatT + (size_t)3136 * 2048, 2048, 512);
    zerofill<<<512, 256, 0, stream>>>(WcatT + (size_t)3648 * 2048);
    wtrans<<<dim3(128, 16), tb, 0, stream>>>(Wukv, WukvT, 512, 4096);

    gemm_bt<bf16><<<dim3(29, 32), 256, 0, stream>>>(xb, 2048, WcatT, 2048, XW, 3712, 2048);
    rope_kernel<<<dim3(17, 1024), dim3(64, 4), 0, stream>>>(XW);
    gemm_kv<<<dim3(32, 32), 256, 0, stream>>>(XW + 3136, 3712, WukvT, 512, kbuf, vT, 512);
    attn_kernel<<<dim3(512), 256, 0, stream>>>(XW, kbuf, vT, attn_out, opart, mlbuf);
    attn_merge<<<dim3(4096, 8), dim3(128, 2), 0, stream>>>(opart, mlbuf, attn_out);
    wtrans<<<dim3(64, 64), tb, 0, stream>>>(Wo, WoT, 2048, 2048);
    gemm_bt<float><<<dim3(16, 32), 256, 0, stream>>>(attn_out, 2048, WoT, 2048, out, 2048, 2048);
}

// Round 7
// 381.298 us; speedup vs baseline: 1.5965x; 1.1997x over previous
//
#include <hip/hip_runtime.h>
#include <hip/hip_bf16.h>

using bf16 = __hip_bfloat16;
typedef __bf16 bf16x8 __attribute__((ext_vector_type(8)));
typedef float f32x4 __attribute__((ext_vector_type(4)));

#define MFMA16(A, B, C) __builtin_amdgcn_mfma_f32_16x16x32_bf16((A), (B), (C), 0, 0, 0)

__device__ __forceinline__ void store_elem(bf16* p, float v) { *p = __float2bfloat16(v); }
__device__ __forceinline__ void store_elem(float* p, float v) { *p = v; }

__device__ __forceinline__ unsigned short f2bu(float x) {
    bf16 t = __float2bfloat16(x);
    return *(unsigned short*)&t;
}

// async global->LDS 16B per lane; LDS dest = wave-uniform base + lane*16.
__device__ __forceinline__ void async_cp16(const bf16* g, bf16* l) {
    __builtin_amdgcn_global_load_lds(
        (const __attribute__((address_space(1))) void*)g,
        (__attribute__((address_space(3))) void*)l, 16, 0, 0);
}

// ---------------------------------------------------------------------------
// prep: fused cvt + weight transposes for WcatT/WukvT + zerofill.
// NOTE: Wo transpose is NOT here — WoT aliases vT, which is live until attn.
// ---------------------------------------------------------------------------
__device__ __forceinline__ void wtrans_body(
    const float* __restrict__ src, bf16* __restrict__ dst, int K, int N,
    int bx, int by, int tx, int ty, bf16 (*t)[33]) {
    int n0 = bx * 32, k0 = by * 32;
    #pragma unroll
    for (int i = 0; i < 4; ++i) {
        int r = ty + i * 8;
        t[r][tx] = __float2bfloat16(src[(size_t)(k0 + r) * N + n0 + tx]);
    }
    __syncthreads();
    #pragma unroll
    for (int i = 0; i < 4; ++i) {
        int r = ty + i * 8;
        dst[(size_t)(n0 + r) * K + k0 + tx] = t[tx][r];
    }
}

__global__ void prep(const float* __restrict__ x, bf16* __restrict__ xb,
                     const float* __restrict__ Wq, const float* __restrict__ Wkr,
                     const float* __restrict__ Wdkv, const float* __restrict__ Wukv,
                     bf16* __restrict__ WcatT, bf16* __restrict__ WukvT) {
    __shared__ bf16 tbuf[32][33];
    int bid = blockIdx.x;
    int tid = threadIdx.x;
    int tx = tid & 31, ty = tid >> 5;
    if (bid < 8192) {                       // cvt x -> xb
        int i = (bid * 256 + tid) * 4;
        float4 v = *(const float4*)(x + i);
        bf16 o[4] = {__float2bfloat16(v.x), __float2bfloat16(v.y),
                     __float2bfloat16(v.z), __float2bfloat16(v.w)};
        *(uint2*)(xb + i) = *(const uint2*)o;
        return;
    }
    bid -= 8192;
    if (bid < 6144) { wtrans_body(Wq, WcatT, 2048, 3072, bid % 96, bid / 96, tx, ty, tbuf); return; }
    bid -= 6144;
    if (bid < 128)  { wtrans_body(Wkr, WcatT + (size_t)3072 * 2048, 2048, 64, bid % 2, bid / 2, tx, ty, tbuf); return; }
    bid -= 128;
    if (bid < 1024) { wtrans_body(Wdkv, WcatT + (size_t)3136 * 2048, 2048, 512, bid % 16, bid / 16, tx, ty, tbuf); return; }
    bid -= 1024;
    if (bid < 1536) {                       // zerofill pad rows 3648..3840
        WcatT[(size_t)3648 * 2048 + bid * 256 + tid] = __float2bfloat16(0.0f);
        return;
    }
    bid -= 1536;
    wtrans_body(Wukv, WukvT, 512, 4096, bid % 128, bid / 128, tx, ty, tbuf);
}

// ---------------------------------------------------------------------------
// Standalone transpose for Wo (launched AFTER attn: WoT aliases dead vT).
// ---------------------------------------------------------------------------
__global__ void wtrans(const float* __restrict__ src, bf16* __restrict__ dst,
                       int K, int N) {
    __shared__ bf16 t[32][33];
    int n0 = blockIdx.x * 32, k0 = blockIdx.y * 32;
    #pragma unroll
    for (int i = 0; i < 4; ++i) {
        int r = threadIdx.y + i * 8;
        t[r][threadIdx.x] = __float2bfloat16(src[(size_t)(k0 + r) * N + n0 + threadIdx.x]);
    }
    __syncthreads();
    #pragma unroll
    for (int i = 0; i < 4; ++i) {
        int r = threadIdx.y + i * 8;
        dst[(size_t)(n0 + r) * K + k0 + threadIdx.x] = t[threadIdx.x][r];
    }
}

// ---------------------------------------------------------------------------
// 256x256 GEMM, BK=64, 8 waves (2Mx4N), 2-phase, 128KB LDS, XOR-swizzled.
// Per K-step: 64 MFMA/wave vs 16 at 128^2 -> 4x better barrier-drain
// amortization. Source-pre-swizzle chunk^(row&7) (rows = 128B = 8 chunks).
// Stores masked to col < Nmax (XW: N=3712; B padded to 3840).
// ---------------------------------------------------------------------------
template <typename CT>
__global__ __launch_bounds__(512, 2) void gemm256(
    const bf16* __restrict__ A, int lda,
    const bf16* __restrict__ Bt, int ldb,
    CT* __restrict__ C, int ldc, int K, int Nmax) {
    __shared__ bf16 smem[65536];    // [A0|A1|B0|B1] x 16384 elems (128KB)
    const int nwg = gridDim.x * gridDim.y;
    const int flat = blockIdx.y * gridDim.x + blockIdx.x;
    const int swz = (flat & 7) * (nwg >> 3) + (flat >> 3);
    const int m0 = (swz / gridDim.x) * 256;
    const int n0 = (swz % gridDim.x) * 256;
    const int tid = threadIdx.x;
    const int lane = tid & 63;
    const int wave = tid >> 6;
    const int wr = wave >> 2;       // 0..1  (M half)
    const int wc = wave & 3;        // 0..3  (N quarter)
    const int lr = lane & 15;
    const int lq = lane >> 4;

    f32x4 acc[8][4] = {};

#define STG256(MATP, LD, ROWBASE, DSTBASE, K0) do {                            \
        _Pragma("unroll")                                                      \
        for (int i_ = 0; i_ < 4; ++i_) {                                       \
            int ig_ = i_ * 8 + wave;                                           \
            int r_ = ig_ * 8 + (lane >> 3);                                    \
            int c_ = (lane & 7) ^ (r_ & 7);                                    \
            async_cp16((MATP) + (size_t)((ROWBASE) + r_) * (LD) + (K0) + c_ * 8,\
                       (DSTBASE) + ig_ * 512);                                 \
        }                                                                      \
    } while (0)

    STG256(A, lda, m0, smem, 0);
    STG256(Bt, ldb, n0, smem + 32768, 0);
    __syncthreads();
    int cur = 0;
    const int nT = K >> 6;
    for (int t = 0; t < nT; ++t) {
        if (t + 1 < nT) {
            STG256(A, lda, m0, smem + (cur ^ 1) * 16384, (t + 1) * 64);
            STG256(Bt, ldb, n0, smem + 32768 + (cur ^ 1) * 16384, (t + 1) * 64);
        }
        const bf16* Ab = smem + cur * 16384;
        const bf16* Bb = smem + 32768 + cur * 16384;
        #pragma unroll
        for (int kk = 0; kk < 2; ++kk) {
            bf16x8 af[8], bfr[4];
            #pragma unroll
            for (int mt = 0; mt < 8; ++mt) {
                int ra = wr * 128 + mt * 16 + lr;
                af[mt] = *(const bf16x8*)(Ab + ra * 64 + ((kk * 4 + lq) ^ (ra & 7)) * 8);
            }
            #pragma unroll
            for (int nt = 0; nt < 4; ++nt) {
                int rb = wc * 64 + nt * 16 + lr;
                bfr[nt] = *(const bf16x8*)(Bb + rb * 64 + ((kk * 4 + lq) ^ (rb & 7)) * 8);
            }
            #pragma unroll
            for (int mt = 0; mt < 8; ++mt)
                #pragma unroll
                for (int nt = 0; nt < 4; ++nt)
                    acc[mt][nt] = MFMA16(af[mt], bfr[nt], acc[mt][nt]);
        }
        __syncthreads();
        cur ^= 1;
    }
#undef STG256
    #pragma unroll
    for (int mt = 0; mt < 8; ++mt)
        #pragma unroll
        for (int nt = 0; nt < 4; ++nt) {
            int col = n0 + wc * 64 + nt * 16 + lr;
            if (col < Nmax) {
                #pragma unroll
                for (int r = 0; r < 4; ++r) {
                    int row = m0 + wr * 128 + mt * 16 + lq * 4 + r;
                    store_elem(C + (size_t)row * ldc + col, acc[mt][nt][r]);
                }
            }
        }
}

// ---------------------------------------------------------------------------
// kv GEMM at 256^2, split epilogue: k_nope -> kbuf, v -> vT. grid (16,16).
// ---------------------------------------------------------------------------
__global__ __launch_bounds__(512, 2) void gemm256_kv(
    const bf16* __restrict__ A, int lda,
    const bf16* __restrict__ Bt, int ldb,
    bf16* __restrict__ kbuf, bf16* __restrict__ vT, int K) {
    __shared__ bf16 smem[65536];
    const int nwg = gridDim.x * gridDim.y;
    const int flat = blockIdx.y * gridDim.x + blockIdx.x;
    const int swz = (flat & 7) * (nwg >> 3) + (flat >> 3);
    const int m0 = (swz / gridDim.x) * 256;
    const int n0 = (swz % gridDim.x) * 256;
    const int tid = threadIdx.x;
    const int lane = tid & 63;
    const int wave = tid >> 6;
    const int wr = wave >> 2;
    const int wc = wave & 3;
    const int lr = lane & 15;
    const int lq = lane >> 4;

    f32x4 acc[8][4] = {};

#define STG256(MATP, LD, ROWBASE, DSTBASE, K0) do {                            \
        _Pragma("unroll")                                                      \
        for (int i_ = 0; i_ < 4; ++i_) {                                       \
            int ig_ = i_ * 8 + wave;                                           \
            int r_ = ig_ * 8 + (lane >> 3);                                    \
            int c_ = (lane & 7) ^ (r_ & 7);                                    \
            async_cp16((MATP) + (size_t)((ROWBASE) + r_) * (LD) + (K0) + c_ * 8,\
                       (DSTBASE) + ig_ * 512);                                 \
        }                                                                      \
    } while (0)

    STG256(A, lda, m0, smem, 0);
    STG256(Bt, ldb, n0, smem + 32768, 0);
    __syncthreads();
    int cur = 0;
    const int nT = K >> 6;
    for (int t = 0; t < nT; ++t) {
        if (t + 1 < nT) {
            STG256(A, lda, m0, smem + (cur ^ 1) * 16384, (t + 1) * 64);
            STG256(Bt, ldb, n0, smem + 32768 + (cur ^ 1) * 16384, (t + 1) * 64);
        }
        const bf16* Ab = smem + cur * 16384;
        const bf16* Bb = smem + 32768 + cur * 16384;
        #pragma unroll
        for (int kk = 0; kk < 2; ++kk) {
            bf16x8 af[8], bfr[4];
            #pragma unroll
            for (int mt = 0; mt < 8; ++mt) {
                int ra = wr * 128 + mt * 16 + lr;
                af[mt] = *(const bf16x8*)(Ab + ra * 64 + ((kk * 4 + lq) ^ (ra & 7)) * 8);
            }
            #pragma unroll
            for (int nt = 0; nt < 4; ++nt) {
                int rb = wc * 64 + nt * 16 + lr;
                bfr[nt] = *(const bf16x8*)(Bb + rb * 64 + ((kk * 4 + lq) ^ (rb & 7)) * 8);
            }
            #pragma unroll
            for (int mt = 0; mt < 8; ++mt)
                #pragma unroll
                for (int nt = 0; nt < 4; ++nt)
                    acc[mt][nt] = MFMA16(af[mt], bfr[nt], acc[mt][nt]);
        }
        __syncthreads();
        cur ^= 1;
    }
#undef STG256
    #pragma unroll
    for (int mt = 0; mt < 8; ++mt)
        #pragma unroll
        for (int nt = 0; nt < 4; ++nt) {
            int colbase = n0 + wc * 64 + nt * 16;
            int h = colbase >> 8;
            int rr = (colbase & 255) + lr;
            #pragma unroll
            for (int r = 0; r < 4; ++r) {
                int row = m0 + wr * 128 + mt * 16 + lq * 4 + r;
                bf16 val = __float2bfloat16(acc[mt][nt][r]);
                if (rr < 128) {
                    kbuf[(size_t)row * 2048 + h * 128 + rr] = val;
                } else {
                    int dv = rr - 128;
                    int b = row >> 11, s = row & 2047;
                    vT[((size_t)((b * 16 + h) * 128 + dv)) * 2048 + s] = val;
                }
            }
        }
}

// ---------------------------------------------------------------------------
// GEMM 128^2 (output GEMM: 256^2 would leave half the CUs idle at grid 128).
// 2-phase + XCD swizzle.
// ---------------------------------------------------------------------------
template <typename CT>
__global__ __launch_bounds__(256) void gemm_bt(
    const bf16* __restrict__ A, int lda,
    const bf16* __restrict__ Bt, int ldb,
    CT* __restrict__ C, int ldc, int K) {
    __shared__ bf16 As[2][128 * 32];
    __shared__ bf16 Bs[2][128 * 32];
    const int nwg = gridDim.x * gridDim.y;
    const int flat = blockIdx.y * gridDim.x + blockIdx.x;
    const int swz = (flat & 7) * (nwg >> 3) + (flat >> 3);
    const int m0 = (swz / gridDim.x) * 128;
    const int n0 = (swz % gridDim.x) * 128;
    const int tid = threadIdx.x;
    const int lane = tid & 63;
    const int wave = tid >> 6;
    const int wm = (wave >> 1) * 64;
    const int wn = (wave & 1) * 64;
    const int lr = lane & 15;
    const int lq = lane >> 4;
    const int sr = tid >> 2;
    const int sc = (tid & 3) * 8;
    const int wbase = wave * 512;

    f32x4 acc[4][4] = {};

#define G_STAGE(BUF, KO) do {                                                  \
        async_cp16(A + (size_t)(m0 + sr) * lda + (KO) + sc, As[BUF] + wbase);  \
        async_cp16(A + (size_t)(m0 + sr + 64) * lda + (KO) + sc,               \
                   As[BUF] + 2048 + wbase);                                    \
        async_cp16(Bt + (size_t)(n0 + sr) * ldb + (KO) + sc, Bs[BUF] + wbase); \
        async_cp16(Bt + (size_t)(n0 + sr + 64) * ldb + (KO) + sc,              \
                   Bs[BUF] + 2048 + wbase);                                    \
    } while (0)

    G_STAGE(0, 0);
    __syncthreads();
    int cur = 0;
    for (int k0 = 0; k0 < K; k0 += 32) {
        if (k0 + 32 < K) G_STAGE(cur ^ 1, k0 + 32);
        bf16x8 af[4], bfr[4];
        #pragma unroll
        for (int t = 0; t < 4; ++t) {
            af[t]  = *(const bf16x8*)(As[cur] + (wm + t * 16 + lr) * 32 + lq * 8);
            bfr[t] = *(const bf16x8*)(Bs[cur] + (wn + t * 16 + lr) * 32 + lq * 8);
        }
        #pragma unroll
        for (int mt = 0; mt < 4; ++mt)
            #pragma unroll
            for (int nt = 0; nt < 4; ++nt)
                acc[mt][nt] = MFMA16(af[mt], bfr[nt], acc[mt][nt]);
        __syncthreads();
        cur ^= 1;
    }
#undef G_STAGE
    #pragma unroll
    for (int mt = 0; mt < 4; ++mt)
        #pragma unroll
        for (int nt = 0; nt < 4; ++nt)
            #pragma unroll
            for (int r = 0; r < 4; ++r) {
                int row = m0 + wm + mt * 16 + lq * 4 + r;
                int col = n0 + wn + nt * 16 + lr;
                store_elem(C + (size_t)row * ldc + col, acc[mt][nt][r]);
            }
}

// ---------------------------------------------------------------------------
__global__ void rope_kernel(bf16* __restrict__ XW) {
    int v = blockIdx.x;
    int row = blockIdx.y * 4 + threadIdx.y;
    int i = threadIdx.x;
    int s = row & 2047;
    int cbase = (v < 16) ? v * 192 + 128 : 3072;
    size_t base = (size_t)row * 3712 + cbase;
    float xi = __bfloat162float(XW[base + i]);
    float xp = __shfl_xor(xi, 32);
    int j = i & 31;
    float inv = exp2f(-(float)j * (13.287712379549449f / 32.0f));
    float ang = (float)s * inv;
    float c = cosf(ang), sn = sinf(ang);
    float res = (i < 32) ? (xi * c - xp * sn) : (xi * c + xp * sn);
    XW[base + i] = __float2bfloat16(res);
}

// ---------------------------------------------------------------------------
// Flash attention (R4 structure, unchanged): K AND V block-cooperatively
// staged via global_load_lds; rope in registers; no spill. Block = (bh, pair
// (U,15-U), key half) -> exactly 17 tiles each. 512 blocks x 4 waves.
// ---------------------------------------------------------------------------
__global__ __launch_bounds__(256, 2) void attn_kernel(
    const bf16* __restrict__ XW, const bf16* __restrict__ kbuf,
    const bf16* __restrict__ vT, bf16* __restrict__ attn_out,
    bf16* __restrict__ opart, float* __restrict__ mlbuf) {
    const int bid = blockIdx.x;
    const int half = bid >> 8;          // key-chunk index
    const int rem = bid & 255;
    const int bh = rem & 31;            // bid%8 == bh%8 -> XCD clustering
    const int p = rem >> 5;             // big-unit pair in [0,8)
    const int b = bh >> 4, h = bh & 15;
    const int tid = threadIdx.x;
    const int wave = tid >> 6;
    const int lane = tid & 63;
    const int lr = lane & 15, lq = lane >> 4;

    __shared__ bf16 Ks[2][64 * 128];    // K-nope tile, swizzled, dbuf (32KB)
    __shared__ bf16 Vs[128 * 64];       // V^T tile, swizzled, single (16KB)
    __shared__ bf16 Pm[4 * 32 * 72];    // per-wave 32x72 P; 16x136 Tr epilogue
    bf16* Pw = Pm + wave * (32 * 72);

    const bf16* xwb = XW + (size_t)b * 2048 * 3712;
    const bf16* kb  = kbuf + (size_t)b * 2048 * 2048 + h * 128;
    const bf16* rp  = xwb + 3072;       // k_rope columns
    const bf16* vTb = vT + (size_t)bh * 128 * 2048;

    const float sc2 = 0.07216878364870323f * 1.4426950408889634f;  // scale*log2e

    const int s_rsub = lane >> 4;
    const int s_j    = lane & 15;
#define STAGE_K(N0, BUF) do {                                                  \
        _Pragma("unroll")                                                      \
        for (int k_ = 0; k_ < 4; ++k_) {                                       \
            int i_ = wave * 4 + k_;                                            \
            int r_ = i_ * 4 + s_rsub;                                          \
            int j_ = s_j ^ (r_ & 7);                                           \
            async_cp16(kb + (size_t)((N0) + r_) * 2048 + j_ * 8,               \
                       (BUF) + i_ * 512);                                      \
        }                                                                      \
    } while (0)

#define STAGE_V(N0) do {                                                       \
        _Pragma("unroll")                                                      \
        for (int k_ = 0; k_ < 4; ++k_) {                                       \
            int i_ = wave * 4 + k_;                                            \
            int r_ = i_ * 8 + (lane >> 3);                                     \
            int j_ = (lane & 7) ^ (r_ & 7);                                    \
            async_cp16(vTb + (size_t)r_ * 2048 + (N0) + j_ * 8,                \
                       Vs + i_ * 512);                                         \
        }                                                                      \
    } while (0)

    const int rs = lr & 7;
    int koff[4];
    #pragma unroll
    for (int c = 0; c < 4; ++c) koff[c] = ((c * 4 + lq) ^ rs) * 8;
    int voff[2];
    voff[0] = (lq ^ rs) * 8;
    voff[1] = ((4 + lq) ^ rs) * 8;

    #pragma unroll 1
    for (int ph = 0; ph < 2; ++ph) {
        const int u = ph ? (15 - p) : p;       // big unit in [0,16)
        const int qw = u * 128 + wave * 32;    // this wave's first q row
        const int hnt = u + 1;                 // tiles per half
        const int t0 = half ? hnt : 0;
        const int t1 = half ? (2 * u + 2) : hnt;

        // Q B-frags: [n=q(lane&15)][k=lq*8..], 2 nf groups x 6 feature chunks
        bf16x8 qf[2][6];
        #pragma unroll
        for (int nf = 0; nf < 2; ++nf) {
            size_t ro = (size_t)(qw + nf * 16 + lr) * 3712 + h * 192;
            #pragma unroll
            for (int c = 0; c < 6; ++c)
                qf[nf][c] = *(const bf16x8*)(xwb + ro + c * 32 + lq * 8);
        }

        f32x4 o[2][8] = {};      // O^T: [nf][dt], col=q, row=dv
        float m_i[2], l_i[2];
        m_i[0] = m_i[1] = -1e30f;
        l_i[0] = l_i[1] = 0.0f;

        STAGE_K(t0 * 64, Ks[0]);
        int par = 0;

        for (int t = t0; t < t1; ++t) {
            const int n0 = t * 64;
            __syncthreads();    // A: staging drained (Ks[par] ready, Vs free)

            bf16x8 rf[2][4];
            #pragma unroll
            for (int c = 0; c < 2; ++c)
                #pragma unroll
                for (int mt = 0; mt < 4; ++mt)
                    rf[c][mt] = *(const bf16x8*)(rp + (size_t)(n0 + mt * 16 + lr) * 3712 + c * 32 + lq * 8);

            STAGE_V(n0);
            if (t + 1 < t1) STAGE_K((t + 1) * 64, Ks[par ^ 1]);

            if (n0 < qw + 32) {  // wave-uniform: skip fully-masked tiles
                const bf16* Kc = Ks[par];
                f32x4 st[4][2] = {};   // [mt(key)][nf(q)]
                __builtin_amdgcn_s_setprio(1);
                #pragma unroll
                for (int c = 0; c < 4; ++c) {
                    #pragma unroll
                    for (int mt = 0; mt < 4; ++mt) {
                        bf16x8 kf = *(const bf16x8*)(Kc + (mt * 16 + lr) * 128 + koff[c]);
                        st[mt][0] = MFMA16(kf, qf[0][c], st[mt][0]);
                        st[mt][1] = MFMA16(kf, qf[1][c], st[mt][1]);
                    }
                }
                #pragma unroll
                for (int c = 0; c < 2; ++c) {
                    #pragma unroll
                    for (int mt = 0; mt < 4; ++mt) {
                        st[mt][0] = MFMA16(rf[c][mt], qf[0][c + 4], st[mt][0]);
                        st[mt][1] = MFMA16(rf[c][mt], qf[1][c + 4], st[mt][1]);
                    }
                }
                __builtin_amdgcn_s_setprio(0);

                #pragma unroll
                for (int nf = 0; nf < 2; ++nf) {
                    int q = qw + nf * 16 + lr;
                    f32x4 a[4];
                    #pragma unroll
                    for (int mt = 0; mt < 4; ++mt) a[mt] = st[mt][nf];
                    if (n0 + 63 > qw + nf * 16) {   // diagonal tile only
                        #pragma unroll
                        for (int mt = 0; mt < 4; ++mt)
                            #pragma unroll
                            for (int r = 0; r < 4; ++r) {
                                int kid = n0 + mt * 16 + lq * 4 + r;
                                if (kid > q) a[mt][r] = -1e30f;
                            }
                    }
                    f32x4 m4 = a[0];
                    #pragma unroll
                    for (int mt = 1; mt < 4; ++mt)
                        #pragma unroll
                        for (int r = 0; r < 4; ++r) m4[r] = fmaxf(m4[r], a[mt][r]);
                    float vm = fmaxf(fmaxf(m4[0], m4[1]), fmaxf(m4[2], m4[3]));
                    vm = fmaxf(vm, __shfl_xor(vm, 16));
                    vm = fmaxf(vm, __shfl_xor(vm, 32));
                    vm *= sc2;
                    // T13 defer-max: only rescale when the max actually grows.
                    if (__any(vm > m_i[nf] + 8.0f)) {
                        float mnew = fmaxf(m_i[nf], vm);
                        float alpha = exp2f(m_i[nf] - mnew);
                        m_i[nf] = mnew;
                        l_i[nf] *= alpha;
                        #pragma unroll
                        for (int dt = 0; dt < 8; ++dt)
                            #pragma unroll
                            for (int r = 0; r < 4; ++r) o[nf][dt][r] *= alpha;
                    }
                    float mi = m_i[nf];
                    float ps = 0.0f;
                    #pragma unroll
                    for (int mt = 0; mt < 4; ++mt) {
                        unsigned short pk[4];
                        #pragma unroll
                        for (int r = 0; r < 4; ++r) {
                            float pv = exp2f(fmaf(a[mt][r], sc2, -mi));
                            ps += pv;
                            pk[r] = f2bu(pv);
                        }
                        *(uint2*)((unsigned short*)Pw + (nf * 16 + lr) * 72 + mt * 16 + lq * 4) =
                            *(uint2*)pk;
                    }
                    ps += __shfl_xor(ps, 16);
                    ps += __shfl_xor(ps, 32);
                    l_i[nf] += ps;
                }
            }

            __syncthreads();    // B: V(t) staged (and K(t+1), early); P visible

            if (n0 < qw + 32) {
                bf16x8 ptf[2][2];
                #pragma unroll
                for (int nf = 0; nf < 2; ++nf)
                    #pragma unroll
                    for (int kt = 0; kt < 2; ++kt)
                        ptf[nf][kt] = *(const bf16x8*)(Pw + (nf * 16 + lr) * 72 + kt * 32 + lq * 8);
                __builtin_amdgcn_s_setprio(1);
                #pragma unroll
                for (int kt = 0; kt < 2; ++kt)
                    #pragma unroll
                    for (int dt = 0; dt < 8; ++dt) {
                        bf16x8 vfr = *(const bf16x8*)(Vs + (dt * 16 + lr) * 64 + voff[kt]);
                        o[0][dt] = MFMA16(vfr, ptf[0][kt], o[0][dt]);
                        o[1][dt] = MFMA16(vfr, ptf[1][kt], o[1][dt]);
                    }
                __builtin_amdgcn_s_setprio(0);
            }
            par ^= 1;
        }

        // ---- epilogue: O^T -> O via per-wave LDS transpose, partial store ----
        #pragma unroll
        for (int nf = 0; nf < 2; ++nf) {
            float l = l_i[nf];
            float wsc = (l > 0.0f) ? (1.0f / l) : 0.0f;
            float sst = (l > 0.0f) ? (m_i[nf] + log2f(l)) : -1e30f;
            __asm__ volatile("s_waitcnt lgkmcnt(0)" ::: "memory");
            #pragma unroll
            for (int dt = 0; dt < 8; ++dt) {
                unsigned short pk[4];
                #pragma unroll
                for (int r = 0; r < 4; ++r) pk[r] = f2bu(o[nf][dt][r] * wsc);
                *(uint2*)((unsigned short*)Pw + lr * 136 + dt * 16 + lq * 4) = *(uint2*)pk;
            }
            __asm__ volatile("s_waitcnt lgkmcnt(0)" ::: "memory");
            int ql = lane >> 2, cs = (lane & 3) * 32;
            int qrow = qw + nf * 16 + ql;
            uint4 d[4];
            #pragma unroll
            for (int k = 0; k < 4; ++k)
                d[k] = *(const uint4*)(Pw + ql * 136 + cs + k * 8);
            bf16* dst = (half ? opart : attn_out) +
                        (size_t)(b * 2048 + qrow) * 2048 + h * 128 + cs;
            #pragma unroll
            for (int k = 0; k < 4; ++k) *(uint4*)(dst + k * 8) = d[k];
            if (lane < 16) {
                int q2 = qw + nf * 16 + lane;
                mlbuf[((size_t)(b * 2048 + q2) * 16 + h) * 2 + half] = sst;
            }
        }
    }
#undef STAGE_K
#undef STAGE_V
}

// ---------------------------------------------------------------------------
// Merge the two key-chunk partials for every q row. s = m + log2(l) per chunk
// (log2 domain); partials are already normalized by their own l.
// ---------------------------------------------------------------------------
__global__ void attn_merge(const bf16* __restrict__ opart,
                           const float* __restrict__ mlbuf,
                           bf16* __restrict__ attn_out) {
    int bs = blockIdx.x;            // b*2048 + s
    int h = blockIdx.y * 2 + threadIdx.y;
    int tx = threadIdx.x;
    const float* mlp = mlbuf + ((size_t)bs * 16 + h) * 2;
    float s0 = mlp[0], s1 = mlp[1];
    size_t off = (size_t)bs * 2048 + h * 128 + tx;
    float o0 = __bfloat162float(attn_out[off]);
    float o1 = __bfloat162float(opart[off]);
    float m = fmaxf(s0, s1);
    float w0 = exp2f(s0 - m);
    float w1 = exp2f(s1 - m);
    float v = (o0 * w0 + o1 * w1) / (w0 + w1);
    attn_out[off] = __float2bfloat16(v);
}

// ---------------------------------------------------------------------------
extern "C" void kernel_launch(void* const* d_in, const int* in_sizes, int n_in,
                              void* d_out, int out_size, void* d_ws, size_t ws_size,
                              hipStream_t stream) {
    const float* x    = (const float*)d_in[0];
    const float* Wq   = (const float*)d_in[1];
    const float* Wdkv = (const float*)d_in[2];
    const float* Wkr  = (const float*)d_in[3];
    const float* Wukv = (const float*)d_in[4];
    const float* Wo   = (const float*)d_in[5];
    float* out = (float*)d_out;

    // Workspace layout (98,041,856 bytes), time-sliced aliasing.
    char* ws = (char*)d_ws;
    bf16* XW       = (bf16*)(ws);
    bf16* kbuf     = (bf16*)(ws + 30408704);
    bf16* vT       = (bf16*)(ws + 47185920);
    bf16* attn_out = (bf16*)(ws + 63963136);
    bf16* opart    = (bf16*)(ws + 80740352);
    float* mlbuf   = (float*)(ws + 97517568);   // 4096*16*2 floats = 512KB
    bf16* xb       = (bf16*)(ws + 30408704);  // alias kbuf (dead before kv gemm)
    bf16* WcatT    = (bf16*)(ws + 47185920);  // alias vT (3840x2048 padded; dead after XW gemm)
    bf16* WukvT    = (bf16*)(ws + 63963136);  // alias attn_out (dead after kv gemm)
    bf16* WoT      = (bf16*)(ws + 47185920);  // alias vT -- ONLY after attn (vT dead)

    // prep grid: 8192 cvt + 6144 Wq + 128 Wkr + 1024 Wdkv + 1536 zfill
    //          + 2048 Wukv = 19072   (Wo transpose deferred: WoT aliases vT)
    prep<<<19072, 256, 0, stream>>>(x, xb, Wq, Wkr, Wdkv, Wukv, WcatT, WukvT);

    // XW = xb @ WcatT^T  (N=3712 real, tiles padded to 3840; masked stores)
    gemm256<bf16><<<dim3(15, 16), 512, 0, stream>>>(xb, 2048, WcatT, 2048,
                                                    XW, 3712, 2048, 3712);
    rope_kernel<<<dim3(17, 1024), dim3(64, 4), 0, stream>>>(XW);
    gemm256_kv<<<dim3(16, 16), 512, 0, stream>>>(XW + 3136, 3712, WukvT, 512,
                                                 kbuf, vT, 512);
    attn_kernel<<<dim3(512), 256, 0, stream>>>(XW, kbuf, vT, attn_out, opart, mlbuf);
    wtrans<<<dim3(64, 64), dim3(32, 8), 0, stream>>>(Wo, WoT, 2048, 2048);
    attn_merge<<<dim3(4096, 8), dim3(128, 2), 0, stream>>>(opart, mlbuf, attn_out);
    gemm_bt<float><<<dim3(16, 32), 256, 0, stream>>>(attn_out, 2048, WoT, 2048,
                                                     out, 2048, 2048);
}